// Round 2
// baseline (517.918 us; speedup 1.0000x reference)
//
#include <hip/hip_runtime.h>
#include <math.h>
#include <stdint.h>

// B=4, N=1024, D=1024, H=16, DH=64, MLP=4096. Inputs fp32, output fp32.
// Round 11: r10 package (never measured — two GPU timeouts) + prep merge.
// (1) 16 dispatches: single prep kernel fuses x|enc fp32->bf16 convert and
// the six 1024^2 weight transposes (role-switch on blockIdx.x).
// (2) Vectorized softmax/ln_res (f32x4 / u16x8) — G13.
// (3) T5 setprio around flash_ca MFMA clusters (m191 +4-7%).
// GEMM engine unchanged (m97-style 128-tile, 2-phase dbuf): the 8-phase
// 256^2 port of FF1 waits for counters to justify the risk.
typedef unsigned short u16;
typedef u16   u16x8 __attribute__((ext_vector_type(8)));
typedef __bf16 bf16x8 __attribute__((ext_vector_type(8)));
typedef float  f32x4 __attribute__((ext_vector_type(4)));

#define B_   4
#define N_   1024
#define D_   1024
#define MLP_ 4096

__device__ __forceinline__ float bf2f(u16 v) {
    unsigned u = ((unsigned)v) << 16;
    return __builtin_bit_cast(float, u);
}
__device__ __forceinline__ u16 f2bf(float f) {
    unsigned u = __builtin_bit_cast(unsigned, f);
    u += 0x7fff + ((u >> 16) & 1);   // RN-even
    return (u16)(u >> 16);
}
__device__ __forceinline__ bf16x8 ld8(const u16* p) {
    return __builtin_bit_cast(bf16x8, *(const u16x8*)p);
}
// async 16B global -> LDS (lds dest = wave-uniform base + lane*16)
__device__ __forceinline__ void gll16(const u16* g, u16* l) {
    __builtin_amdgcn_global_load_lds(
        (const __attribute__((address_space(1))) unsigned int*)g,
        (__attribute__((address_space(3))) unsigned int*)l,
        16, 0, 0);
}

// ---------------------------------------------------------------------------
// Fused prep: blocks [0,4096) convert x|enc fp32->bf16 (8 elems/thread);
// blocks [4096,10240) do the six 1024x1024 weight transposes (fp32->bf16).
// ---------------------------------------------------------------------------
__global__ __launch_bounds__(256)
void prep_all(const float* __restrict__ x, const float* __restrict__ enc,
              u16* __restrict__ xB, u16* __restrict__ encB,
              const float* __restrict__ p0, const float* __restrict__ p1,
              const float* __restrict__ p2, const float* __restrict__ p3,
              const float* __restrict__ p4, const float* __restrict__ p5,
              u16* __restrict__ Wsa, u16* __restrict__ Wca)
{
    __shared__ u16 tile[32][33];
    int bid = blockIdx.x;
    if (bid < 4096) {
        // ---- convert role ----
        const float* in = x; u16* out = xB;
        if (bid >= 2048) { in = enc; out = encB; bid -= 2048; }
        long i = (long)bid * 256 + threadIdx.x;        // < 524288 exactly
        f32x4 a = *(const f32x4*)&in[i * 8];
        f32x4 b = *(const f32x4*)&in[i * 8 + 4];
        u16x8 h;
        h[0] = f2bf(a[0]); h[1] = f2bf(a[1]); h[2] = f2bf(a[2]); h[3] = f2bf(a[3]);
        h[4] = f2bf(b[0]); h[5] = f2bf(b[1]); h[6] = f2bf(b[2]); h[7] = f2bf(b[3]);
        *(u16x8*)&out[i * 8] = h;
        return;
    }
    // ---- weight-transpose role ----
    int sub = bid - 4096;
    const int z = sub >> 10;          // 0..5
    const int t2 = sub & 1023;
    const int bx = (t2 & 31) * 32, by = (t2 >> 5) * 32;
    const float* in = p0;
    if (z == 1) in = p1;
    else if (z == 2) in = p2;
    else if (z == 3) in = p3;
    else if (z == 4) in = p4;
    else if (z == 5) in = p5;
    u16* out = (z < 3) ? Wsa + (long)z * (1 << 20) : Wca + (long)(z - 3) * (1 << 20);
    const int tx = threadIdx.x & 31, ty = threadIdx.x >> 5;
#pragma unroll
    for (int i = ty; i < 32; i += 8)
        tile[i][tx] = f2bf(in[(long)(by + i) * 1024 + bx + tx]);
    __syncthreads();
#pragma unroll
    for (int i = ty; i < 32; i += 8)
        out[(long)(bx + i) * 1024 + by + tx] = tile[tx][i];
}

// ---------------------------------------------------------------------------
// GEMM: C[m,n] = scale*sum_k A[m,k]*Bt[n,k] (+bias)(gelu). A,Bt bf16.
// Tile TM x TN x 32, 4 waves (2x2 of TM/2 x TN/2), 16x16x32 bf16 MFMA,
// global_load_lds width=16, double-buffered K-loop.
// SEL=0: single problem. SEL=1: y-half selects (A0,B0,C0)/(A1,B1,C1).
// SEL=2: z-half selects. Fused dispatches keep grids >=512 at 128x128.
// ---------------------------------------------------------------------------
template<int TM, int TN, int SEL, int OUTF32, int BIAS, int GELU>
__global__ __launch_bounds__(256, (TM + TN >= 256) ? 3 : 4)
void gemm_a(const u16* __restrict__ A0, const u16* __restrict__ A1,
            const u16* __restrict__ B0, const u16* __restrict__ B1,
            void* __restrict__ C0v, void* __restrict__ C1v,
            const float* __restrict__ bias,
            float scale, int K,
            int lda, int ldb, int ldc,
            long sA, long sB, long sC)
{
    constexpr int MT = TM / 32, NT = TN / 32;   // frag tiles per wave
    __shared__ alignas(16) u16 As[2][TM * 32];
    __shared__ alignas(16) u16 Bs[2][TN * 32];
    int by = blockIdx.y, bz = blockIdx.z;
    const u16* A = A0; const u16* Bt = B0; char* Cp = (char*)C0v;
    if (SEL == 1) {
        int half = gridDim.y >> 1;
        if (by >= half) { A = A1; Bt = B1; Cp = (char*)C1v; by -= half; }
    }
    if (SEL == 2) {
        int half = gridDim.z >> 1;
        if (bz >= half) { A = A1; Bt = B1; Cp = (char*)C1v; bz -= half; }
    }
    A += bz * sA;  Bt += bz * sB;  Cp += bz * sC * (OUTF32 ? 4 : 2);
    const int m0 = blockIdx.x * TM, n0 = by * TN;
    const int t = threadIdx.x, lane = t & 63, w = t >> 6;
    const int wr = (w >> 1) * (TM / 2), wc = (w & 1) * (TN / 2);
    const int fr = lane & 15, fq = lane >> 4, fk = fq * 8;
    f32x4 acc[MT][NT] = {};

    // staging: 256 threads x 16B cover 64 rows x 32 cols per pass
    const int r0a = t >> 2, c0a = (t & 3) * 8;
    auto stageA = [&](u16* dst, int k0) {
#pragma unroll
        for (int p = 0; p < TM / 64; p++)
            gll16(A + (long)(m0 + p * 64 + r0a) * lda + k0 + c0a, dst + p * 2048 + w * 512);
    };
    auto stageB = [&](u16* dst, int k0) {
#pragma unroll
        for (int p = 0; p < TN / 64; p++)
            gll16(Bt + (long)(n0 + p * 64 + r0a) * ldb + k0 + c0a, dst + p * 2048 + w * 512);
    };

    stageA(As[0], 0);
    stageB(Bs[0], 0);
    int cur = 0;
    for (int k0 = 0; k0 < K; k0 += 32) {
        __syncthreads();                       // drains vmcnt -> buf[cur] ready
        if (k0 + 32 < K) {
            stageA(As[cur ^ 1], k0 + 32);
            stageB(Bs[cur ^ 1], k0 + 32);
        }
        const u16* as = As[cur];
        const u16* bs = Bs[cur];
        bf16x8 af[MT], bfv[NT];
#pragma unroll
        for (int mt = 0; mt < MT; mt++) af [mt] = ld8(&as[(wr + mt * 16 + fr) * 32 + fk]);
#pragma unroll
        for (int nt = 0; nt < NT; nt++) bfv[nt] = ld8(&bs[(wc + nt * 16 + fr) * 32 + fk]);
#pragma unroll
        for (int mt = 0; mt < MT; mt++)
#pragma unroll
            for (int nt = 0; nt < NT; nt++)
                acc[mt][nt] = __builtin_amdgcn_mfma_f32_16x16x32_bf16(af[mt], bfv[nt], acc[mt][nt], 0, 0, 0);
        cur ^= 1;
    }

    // C/D layout (m89/m91): col = lane&15, row = (lane>>4)*4 + reg.
#pragma unroll
    for (int nt = 0; nt < NT; nt++) {
        const int col = n0 + wc + nt * 16 + fr;
        float bv = 0.f;
        if (BIAS) bv = bias[col];
#pragma unroll
        for (int mt = 0; mt < MT; mt++) {
            const int rbase = m0 + wr + mt * 16 + fq * 4;
#pragma unroll
            for (int r = 0; r < 4; r++) {
                float v = acc[mt][nt][r] * scale;
                if (BIAS) v += bv;
                if (GELU) v = 0.5f * v * (1.0f + erff(v * 0.70710678118654752f));
                long idx = (long)(rbase + r) * ldc + col;
                if (OUTF32) ((float*)Cp)[idx] = v;
                else        ((u16*) Cp)[idx] = f2bf(v);
            }
        }
    }
}

// ---------------------------------------------------------------------------
// 32x32-tile transpose with cast to bf16: out[c, r] = (bf16) in[r, c]
// (kept for the per-batch kcT transpose)
// ---------------------------------------------------------------------------
template<int INF32>
__global__ __launch_bounds__(256)
void transpose_cast(const void* __restrict__ in, u16* __restrict__ out,
                    int R, int C, long sIn, long sOut)
{
    __shared__ u16 tile[32][33];
    const char* ip = (const char*)in + (long)blockIdx.z * sIn * (INF32 ? 4 : 2);
    u16*        op = out + (long)blockIdx.z * sOut;
    const int bx = blockIdx.x * 32, by = blockIdx.y * 32;
    const int tx = threadIdx.x & 31, ty = threadIdx.x >> 5;
#pragma unroll
    for (int i = ty; i < 32; i += 8) {
        long idx = (long)(by + i) * C + bx + tx;
        tile[i][tx] = INF32 ? f2bf(((const float*)ip)[idx]) : ((const u16*)ip)[idx];
    }
    __syncthreads();
#pragma unroll
    for (int i = ty; i < 32; i += 8) op[(long)(bx + i) * R + by + tx] = tile[tx][i];
}

// ---------------------------------------------------------------------------
// w1 [1024,4096] and w2 [4096,1024] transposes fused: grid (128, 32, 2).
// z=0: direct tiles for w1. z=1: remap (bx,by) -> (bx>>2, by*4 + (bx&3)).
// ---------------------------------------------------------------------------
__global__ __launch_bounds__(256)
void transpose_ff(const float* __restrict__ w1, const float* __restrict__ w2,
                  u16* __restrict__ o1, u16* __restrict__ o2)
{
    __shared__ u16 tile[32][33];
    const float* in; u16* out; int R, C, bx, by;
    if (blockIdx.z == 0) {
        in = w1; out = o1; R = 1024; C = 4096;
        bx = blockIdx.x; by = blockIdx.y;                 // bx<128, by<32
    } else {
        in = w2; out = o2; R = 4096; C = 1024;
        bx = blockIdx.x >> 2; by = blockIdx.y * 4 + (blockIdx.x & 3);  // bx<32, by<128
    }
    const int x0 = bx * 32, y0 = by * 32;
    const int tx = threadIdx.x & 31, ty = threadIdx.x >> 5;
#pragma unroll
    for (int i = ty; i < 32; i += 8)
        tile[i][tx] = f2bf(in[(long)(y0 + i) * C + x0 + tx]);
    __syncthreads();
#pragma unroll
    for (int i = ty; i < 32; i += 8)
        out[(long)(x0 + i) * R + y0 + tx] = tile[tx][i];
}

// ---------------------------------------------------------------------------
// Row softmax: 1024 fp32 in -> 1024 bf16 out; one wave per row.
// Lane owns 16 contiguous cols (f32x4 loads / u16x8 stores).
// ---------------------------------------------------------------------------
__global__ __launch_bounds__(256)
void softmax_1024(const float* __restrict__ in, u16* __restrict__ out)
{
    const int lane = threadIdx.x & 63, wv = threadIdx.x >> 6;
    const long row = (long)blockIdx.x * 4 + wv;
    const float* p = in + row * 1024 + lane * 16;
    float v[16];
#pragma unroll
    for (int q = 0; q < 4; q++) {
        f32x4 a = *(const f32x4*)(p + q * 4);
#pragma unroll
        for (int e = 0; e < 4; e++) v[q * 4 + e] = a[e];
    }
    float mx = v[0];
#pragma unroll
    for (int i = 1; i < 16; i++) mx = fmaxf(mx, v[i]);
#pragma unroll
    for (int off = 32; off; off >>= 1) mx = fmaxf(mx, __shfl_xor(mx, off, 64));
    float s = 0.f;
#pragma unroll
    for (int i = 0; i < 16; i++) { v[i] = __expf(v[i] - mx); s += v[i]; }
#pragma unroll
    for (int off = 32; off; off >>= 1) s += __shfl_xor(s, off, 64);
    const float inv = 1.0f / s;
    u16* qp = out + row * 1024 + lane * 16;
#pragma unroll
    for (int q = 0; q < 2; q++) {
        u16x8 o;
#pragma unroll
        for (int e = 0; e < 8; e++) o[e] = f2bf(v[q * 8 + e] * inv);
        *(u16x8*)(qp + q * 8) = o;
    }
}

// ---------------------------------------------------------------------------
// out = LayerNorm(a + res) * g + beta ; rows of 1024; one wave per row.
// Lane owns 16 contiguous cols -> all loads/stores 16B-vectorized.
// ---------------------------------------------------------------------------
template<int AF32, int RESF32, int OUTF32>
__global__ __launch_bounds__(256)
void ln_res(const void* __restrict__ Av, const void* __restrict__ Rv,
            const float* __restrict__ g, const float* __restrict__ be,
            void* __restrict__ out)
{
    const int lane = threadIdx.x & 63, wv = threadIdx.x >> 6;
    const long row = (long)blockIdx.x * 4 + wv;
    const long off = row * 1024 + lane * 16;
    const int c0 = lane * 16;
    float v[16];
    if (AF32) {
#pragma unroll
        for (int q = 0; q < 4; q++) {
            f32x4 a = *((const f32x4*)((const float*)Av + off) + q);
#pragma unroll
            for (int e = 0; e < 4; e++) v[q * 4 + e] = a[e];
        }
    } else {
#pragma unroll
        for (int q = 0; q < 2; q++) {
            u16x8 a = *((const u16x8*)((const u16*)Av + off) + q);
#pragma unroll
            for (int e = 0; e < 8; e++) v[q * 8 + e] = bf2f(a[e]);
        }
    }
    if (RESF32) {
#pragma unroll
        for (int q = 0; q < 4; q++) {
            f32x4 a = *((const f32x4*)((const float*)Rv + off) + q);
#pragma unroll
            for (int e = 0; e < 4; e++) v[q * 4 + e] += a[e];
        }
    } else {
#pragma unroll
        for (int q = 0; q < 2; q++) {
            u16x8 a = *((const u16x8*)((const u16*)Rv + off) + q);
#pragma unroll
            for (int e = 0; e < 8; e++) v[q * 8 + e] += bf2f(a[e]);
        }
    }
    float s = 0.f;
#pragma unroll
    for (int i = 0; i < 16; i++) s += v[i];
#pragma unroll
    for (int o = 32; o; o >>= 1) s += __shfl_xor(s, o, 64);
    const float mu = s * (1.f / 1024.f);
    float s2 = 0.f;
#pragma unroll
    for (int i = 0; i < 16; i++) { float d = v[i] - mu; s2 += d * d; }
#pragma unroll
    for (int o = 32; o; o >>= 1) s2 += __shfl_xor(s2, o, 64);
    const float rs = rsqrtf(s2 * (1.f / 1024.f) + 1e-5f);

    float ov[16];
#pragma unroll
    for (int q = 0; q < 4; q++) {
        f32x4 gv = *(const f32x4*)&g[c0 + q * 4];
        f32x4 bv = *(const f32x4*)&be[c0 + q * 4];
#pragma unroll
        for (int e = 0; e < 4; e++)
            ov[q * 4 + e] = (v[q * 4 + e] - mu) * rs * gv[e] + bv[e];
    }
    if (OUTF32) {
#pragma unroll
        for (int q = 0; q < 4; q++) {
            f32x4 o;
#pragma unroll
            for (int e = 0; e < 4; e++) o[e] = ov[q * 4 + e];
            *((f32x4*)((float*)out + off) + q) = o;
        }
    } else {
#pragma unroll
        for (int q = 0; q < 2; q++) {
            u16x8 o;
#pragma unroll
            for (int e = 0; e < 8; e++) o[e] = f2bf(ov[q * 8 + e]);
            *((u16x8*)((u16*)out + off) + q) = o;
        }
    }
}

// ---------------------------------------------------------------------------
// Flash cross-attention (r8 + T5 setprio). Grid: (8 i-tiles, 16 heads, 4 b).
// One-pass softmax (|dots| <~ 8 by construction), reg-resident Q frags,
// async dbuf K/V staging.
// ---------------------------------------------------------------------------
__global__ __launch_bounds__(256, 3)
void flash_ca(const u16* __restrict__ P, const u16* __restrict__ Kc,
              const u16* __restrict__ VT, u16* __restrict__ O)
{
    __shared__ alignas(16) u16 Ks[2][64 * 64];
    __shared__ alignas(16) u16 Vs[2][64 * 64];   // [d][j]
    __shared__ alignas(16) u16 Ps[128 * 72];     // per-wave 32-row strips
    const int b = blockIdx.z, h = blockIdx.y, it = blockIdx.x;
    const long base = (long)b * N_ * D_;
    const int t = threadIdx.x, lane = t & 63, w = t >> 6;
    const int fr = lane & 15, fq = lane >> 4;

    bf16x8 qf[2][2];
#pragma unroll
    for (int mt = 0; mt < 2; mt++)
#pragma unroll
        for (int hf = 0; hf < 2; hf++)
            qf[mt][hf] = ld8(&P[base + (long)(it * 128 + w * 32 + mt * 16 + fr) * D_
                                + h * 64 + hf * 32 + fq * 8]);

    auto stageK = [&](int buf, int jt) {
#pragma unroll
        for (int p = 0; p < 2; p++)
            gll16(Kc + base + (long)(jt * 64 + p * 32 + (t >> 3)) * D_ + h * 64 + (t & 7) * 8,
                  &Ks[buf][p * 2048 + w * 512]);
    };
    auto stageV = [&](int buf, int jt) {
#pragma unroll
        for (int p = 0; p < 2; p++)
            gll16(VT + base + (long)(h * 64 + p * 32 + (t >> 3)) * D_ + jt * 64 + (t & 7) * 8,
                  &Vs[buf][p * 2048 + w * 512]);
    };

    f32x4 o[2][4] = {};
    float l_lane[2][4] = {};

    stageK(0, 0); stageV(0, 0);
    int cur = 0;
    for (int jt = 0; jt < 16; jt++) {
        __syncthreads();
        if (jt + 1 < 16) { stageK(cur ^ 1, jt + 1); stageV(cur ^ 1, jt + 1); }
        const u16* ks = Ks[cur];
        const u16* vs = Vs[cur];

        f32x4 st[2][4] = {};
        __builtin_amdgcn_s_setprio(1);
#pragma unroll
        for (int nt = 0; nt < 4; nt++) {
            bf16x8 b0 = ld8(&ks[(nt * 16 + fr) * 64 + fq * 8]);
            bf16x8 b1 = ld8(&ks[(nt * 16 + fr) * 64 + 32 + fq * 8]);
#pragma unroll
            for (int mt = 0; mt < 2; mt++) {
                st[mt][nt] = __builtin_amdgcn_mfma_f32_16x16x32_bf16(qf[mt][0], b0, st[mt][nt], 0, 0, 0);
                st[mt][nt] = __builtin_amdgcn_mfma_f32_16x16x32_bf16(qf[mt][1], b1, st[mt][nt], 0, 0, 0);
            }
        }
        __builtin_amdgcn_s_setprio(0);
#pragma unroll
        for (int mt = 0; mt < 2; mt++)
#pragma unroll
            for (int nt = 0; nt < 4; nt++)
#pragma unroll
                for (int r = 0; r < 4; r++) {
                    float e = __expf(st[mt][nt][r]);
                    l_lane[mt][r] += e;
                    Ps[(w * 32 + mt * 16 + fq * 4 + r) * 72 + nt * 16 + fr] = f2bf(e);
                }
        __asm__ volatile("s_waitcnt lgkmcnt(0)" ::: "memory");
        bf16x8 vf[4][2];
#pragma unroll
        for (int dt = 0; dt < 4; dt++) {
            vf[dt][0] = ld8(&vs[(dt * 16 + fr) * 64 + fq * 8]);
            vf[dt][1] = ld8(&vs[(dt * 16 + fr) * 64 + 32 + fq * 8]);
        }
        __builtin_amdgcn_s_setprio(1);
#pragma unroll
        for (int mt = 0; mt < 2; mt++) {
            bf16x8 p0 = ld8(&Ps[(w * 32 + mt * 16 + fr) * 72 + fq * 8]);
            bf16x8 p1 = ld8(&Ps[(w * 32 + mt * 16 + fr) * 72 + 32 + fq * 8]);
#pragma unroll
            for (int dt = 0; dt < 4; dt++) {
                o[mt][dt] = __builtin_amdgcn_mfma_f32_16x16x32_bf16(p0, vf[dt][0], o[mt][dt], 0, 0, 0);
                o[mt][dt] = __builtin_amdgcn_mfma_f32_16x16x32_bf16(p1, vf[dt][1], o[mt][dt], 0, 0, 0);
            }
        }
        __builtin_amdgcn_s_setprio(0);
        cur ^= 1;
    }
#pragma unroll
    for (int mt = 0; mt < 2; mt++)
#pragma unroll
        for (int r = 0; r < 4; r++) {
            float lt = l_lane[mt][r];
#pragma unroll
            for (int off = 1; off < 16; off <<= 1) lt += __shfl_xor(lt, off, 64);
            l_lane[mt][r] = 1.0f / lt;
        }
#pragma unroll
    for (int mt = 0; mt < 2; mt++)
#pragma unroll
        for (int dt = 0; dt < 4; dt++)
#pragma unroll
            for (int r = 0; r < 4; r++)
                O[base + (long)(it * 128 + w * 32 + mt * 16 + fq * 4 + r) * D_
                  + h * 64 + dt * 16 + fr] = f2bf(o[mt][dt][r] * l_lane[mt][r]);
}

// ---------------------------------------------------------------------------
extern "C" void kernel_launch(void* const* d_in, const int* in_sizes, int n_in,
                              void* d_out, int out_size, void* d_ws, size_t ws_size,
                              hipStream_t stream)
{
    const float* x     = (const float*)d_in[0];
    const float* enc   = (const float*)d_in[1];
    const float* sa_wq = (const float*)d_in[2];
    const float* sa_wk = (const float*)d_in[3];
    const float* sa_wv = (const float*)d_in[4];
    const float* sa_g  = (const float*)d_in[5];
    const float* sa_b  = (const float*)d_in[6];
    const float* ca_wq = (const float*)d_in[7];
    const float* ca_wk = (const float*)d_in[8];
    const float* ca_wv = (const float*)d_in[9];
    const float* ca_g  = (const float*)d_in[10];
    const float* ca_b  = (const float*)d_in[11];
    const float* w1    = (const float*)d_in[12];
    const float* b1    = (const float*)d_in[13];
    const float* w2    = (const float*)d_in[14];
    const float* b2    = (const float*)d_in[15];
    const float* ff_g  = (const float*)d_in[16];
    const float* ff_b  = (const float*)d_in[17];

    // 76 MB workspace, lifetime-overlaid (MB offsets):
    //  0- 8 xB -> attnB(attn->P) -> w2T
    //  8-16 encB -> w1T
    // 16-22 Wsa ; 22-28 Wca ; 16-32 h2F (after CA)
    // 28-36 qB_sa -> E(saln) -> flash O
    // 36-44 kB_sa -> qB(ca) -> calnB
    // 44-52 vTB -> kB(ca) ; 44-76 h1B (FF)
    // 52-60 vcTB
    // 60-76 scF (fp32) ; 60-68 kcT (CA)
    char* ws = (char*)d_ws;
    const size_t MB = 1ull << 20;
    u16*  xB    = (u16*)(ws + 0 * MB);
    u16*  attnB = (u16*)(ws + 0 * MB);
    u16*  w2T   = (u16*)(ws + 0 * MB);
    u16*  encB  = (u16*)(ws + 8 * MB);
    u16*  w1T   = (u16*)(ws + 8 * MB);
    u16*  Wsa   = (u16*)(ws + 16 * MB);   // q@+0, k@+1M, v@+2M elems
    u16*  Wca   = (u16*)(ws + 22 * MB);
    float* h2F  = (float*)(ws + 16 * MB);
    u16*  qBsa  = (u16*)(ws + 28 * MB);
    u16*  E     = (u16*)(ws + 28 * MB);   // saln, then flash O
    u16*  kBsa  = (u16*)(ws + 36 * MB);
    u16*  qBca  = (u16*)(ws + 36 * MB);
    u16*  calnB = (u16*)(ws + 36 * MB);
    u16*  vTB   = (u16*)(ws + 44 * MB);
    u16*  kBca  = (u16*)(ws + 44 * MB);
    u16*  h1B   = (u16*)(ws + 44 * MB);
    u16*  vcTB  = (u16*)(ws + 52 * MB);
    float* scF  = (float*)(ws + 60 * MB);
    u16*  kcT   = (u16*)(ws + 60 * MB);

    const dim3 blk(256, 1, 1);
    const long M1 = (long)N_ * D_;        // 1M elems, per-batch stride
    const long W1M = (long)1024 * 1024;   // weight matrix elems

    // 0) fused prep: x|enc converts + six weight transposes (one dispatch)
    prep_all<<<dim3(10240, 1, 1), blk, 0, stream>>>(
        x, enc, xB, encB, sa_wq, sa_wk, sa_wv, ca_wq, ca_wk, ca_wv, Wsa, Wca);

    // 2) q|k fused (y-half): [4096,1024] each. grid 32x16 = 512, 128x128.
    gemm_a<128,128,1,0,0,0><<<dim3(32, 16, 1), blk, 0, stream>>>(
        xB, xB, Wsa, Wsa + W1M, qBsa, kBsa, nullptr,
        1.f, 1024, 1024, 1024, 1024, 0, 0, 0);
    // 3) vT|vcT fused (z-half): vT[b]=WsaV @ xB[b]^T ; vcT[b]=WcaV @ encB[b]^T
    gemm_a<128,128,2,0,0,0><<<dim3(8, 8, 8), blk, 0, stream>>>(
        Wsa + 2 * W1M, Wca + 2 * W1M, xB, encB, vTB, vcTB, nullptr,
        1.f, 1024, 1024, 1024, 1024, 0, M1, M1);
    // 4) scores = q k^T / 32 (fp32). grid 8x16x4 = 512, 128x64.
    gemm_a<128,64,0,1,0,0><<<dim3(8, 16, 4), blk, 0, stream>>>(
        qBsa, nullptr, kBsa, nullptr, scF, nullptr, nullptr,
        0.03125f, 1024, 1024, 1024, 1024, M1, M1, M1);
    softmax_1024<<<dim3(1024, 1, 1), blk, 0, stream>>>(scF, attnB);
    // 5) sa_pre = attn @ v (fp32)
    gemm_a<128,64,0,1,0,0><<<dim3(8, 16, 4), blk, 0, stream>>>(
        attnB, nullptr, vTB, nullptr, scF, nullptr, nullptr,
        1.f, 1024, 1024, 1024, 1024, M1, M1, M1);
    ln_res<1,1,0><<<dim3(1024, 1, 1), blk, 0, stream>>>(scF, x, sa_g, sa_b, E);

    // 6) qc|kc fused (y-half): qc = saln @ Wq ; kc = encB @ Wk. grid 32x16.
    gemm_a<128,128,1,0,0,0><<<dim3(32, 16, 1), blk, 0, stream>>>(
        E, encB, Wca, Wca + W1M, qBca, kBca, nullptr,
        1.f, 1024, 1024, 1024, 1024, 0, 0, 0);
    // 7) kcT per batch (scF dead)
    transpose_cast<0><<<dim3(32, 32, 4), blk, 0, stream>>>(kBca, kcT, 1024, 1024, M1, M1);
    // 8) P = (qc @ kc) / 64
    gemm_a<128,64,0,0,0,0><<<dim3(8, 16, 4), blk, 0, stream>>>(
        qBca, nullptr, kcT, nullptr, attnB, nullptr, nullptr,
        0.015625f, 1024, 1024, 1024, 1024, M1, M1, M1);
    // 9) flash cross-attn -> O (over saln region)
    flash_ca<<<dim3(8, 16, 4), blk, 0, stream>>>(attnB, kBca, vcTB, E);
    ln_res<0,1,0><<<dim3(1024, 1, 1), blk, 0, stream>>>(E, enc, ca_g, ca_b, calnB);

    // 10) FeedForward (w1T|w2T fused in one dispatch)
    transpose_ff<<<dim3(128, 32, 2), blk, 0, stream>>>(w1, w2, w1T, w2T);
    gemm_a<128,128,0,0,1,1><<<dim3(32, 32, 1), blk, 0, stream>>>(
        calnB, nullptr, w1T, nullptr, h1B, nullptr, b1,
        1.f, 1024, 1024, 1024, 4096, 0, 0, 0);
    gemm_a<128,64,0,1,1,0><<<dim3(32, 16, 1), blk, 0, stream>>>(
        h1B, nullptr, w2T, nullptr, h2F, nullptr, b2,
        1.f, 4096, 4096, 4096, 1024, 0, 0, 0);
    ln_res<1,0,1><<<dim3(1024, 1, 1), blk, 0, stream>>>(h2F, calnB, ff_g, ff_b, (float*)d_out);
}

// Round 3
// 503.326 us; speedup vs baseline: 1.0290x; 1.0290x over previous
//
#include <hip/hip_runtime.h>
#include <math.h>
#include <stdint.h>

// B=4, N=1024, D=1024, H=16, DH=64, MLP=4096. Inputs fp32, output fp32.
// Round 12: counters (r2) show FF2 = 72us @ MfmaUtil 17.5%, occ 20%, HBM 12%
// -> latency/bubble-bound GEMMs at 2 blocks/CU. Package:
// (1) BK=64 (halved barrier count) for scores/attn@v/P/FF2 (128x64, LDS 48KB,
//     grid-limited 2/CU so no occupancy loss) and qc|kc (128x128, 64KB, 2/CU).
// (2) q|k + vT|vcT merged into one 1024-block dispatch (BK=32, bounds 3)
//     -> 3 blocks/CU for that phase. 15 dispatches total.
// FF1 untouched (1024 blocks @ 3/CU; BK=64 would cost a resident block).
typedef unsigned short u16;
typedef u16   u16x8 __attribute__((ext_vector_type(8)));
typedef __bf16 bf16x8 __attribute__((ext_vector_type(8)));
typedef float  f32x4 __attribute__((ext_vector_type(4)));

#define B_   4
#define N_   1024
#define D_   1024
#define MLP_ 4096

__device__ __forceinline__ float bf2f(u16 v) {
    unsigned u = ((unsigned)v) << 16;
    return __builtin_bit_cast(float, u);
}
__device__ __forceinline__ u16 f2bf(float f) {
    unsigned u = __builtin_bit_cast(unsigned, f);
    u += 0x7fff + ((u >> 16) & 1);   // RN-even
    return (u16)(u >> 16);
}
__device__ __forceinline__ bf16x8 ld8(const u16* p) {
    return __builtin_bit_cast(bf16x8, *(const u16x8*)p);
}
// async 16B global -> LDS (lds dest = wave-uniform base + lane*16)
__device__ __forceinline__ void gll16(const u16* g, u16* l) {
    __builtin_amdgcn_global_load_lds(
        (const __attribute__((address_space(1))) unsigned int*)g,
        (__attribute__((address_space(3))) unsigned int*)l,
        16, 0, 0);
}

// ---------------------------------------------------------------------------
// Fused prep: blocks [0,4096) convert x|enc fp32->bf16 (8 elems/thread);
// blocks [4096,10240) do the six 1024x1024 weight transposes (fp32->bf16).
// ---------------------------------------------------------------------------
__global__ __launch_bounds__(256)
void prep_all(const float* __restrict__ x, const float* __restrict__ enc,
              u16* __restrict__ xB, u16* __restrict__ encB,
              const float* __restrict__ p0, const float* __restrict__ p1,
              const float* __restrict__ p2, const float* __restrict__ p3,
              const float* __restrict__ p4, const float* __restrict__ p5,
              u16* __restrict__ Wsa, u16* __restrict__ Wca)
{
    __shared__ u16 tile[32][33];
    int bid = blockIdx.x;
    if (bid < 4096) {
        // ---- convert role ----
        const float* in = x; u16* out = xB;
        if (bid >= 2048) { in = enc; out = encB; bid -= 2048; }
        long i = (long)bid * 256 + threadIdx.x;        // < 524288 exactly
        f32x4 a = *(const f32x4*)&in[i * 8];
        f32x4 b = *(const f32x4*)&in[i * 8 + 4];
        u16x8 h;
        h[0] = f2bf(a[0]); h[1] = f2bf(a[1]); h[2] = f2bf(a[2]); h[3] = f2bf(a[3]);
        h[4] = f2bf(b[0]); h[5] = f2bf(b[1]); h[6] = f2bf(b[2]); h[7] = f2bf(b[3]);
        *(u16x8*)&out[i * 8] = h;
        return;
    }
    // ---- weight-transpose role ----
    int sub = bid - 4096;
    const int z = sub >> 10;          // 0..5
    const int t2 = sub & 1023;
    const int bx = (t2 & 31) * 32, by = (t2 >> 5) * 32;
    const float* in = p0;
    if (z == 1) in = p1;
    else if (z == 2) in = p2;
    else if (z == 3) in = p3;
    else if (z == 4) in = p4;
    else if (z == 5) in = p5;
    u16* out = (z < 3) ? Wsa + (long)z * (1 << 20) : Wca + (long)(z - 3) * (1 << 20);
    const int tx = threadIdx.x & 31, ty = threadIdx.x >> 5;
#pragma unroll
    for (int i = ty; i < 32; i += 8)
        tile[i][tx] = f2bf(in[(long)(by + i) * 1024 + bx + tx]);
    __syncthreads();
#pragma unroll
    for (int i = ty; i < 32; i += 8)
        out[(long)(bx + i) * 1024 + by + tx] = tile[tx][i];
}

// ---------------------------------------------------------------------------
// GEMM body: C[m,n] = scale*sum_k A[m,k]*Bt[n,k] (+bias)(gelu). A,Bt bf16.
// Tile TM x TN x BK, 4 waves (2x2 of TM/2 x TN/2), 16x16x32 bf16 MFMA,
// global_load_lds width=16, double-buffered K-loop (1 barrier per BK).
// ---------------------------------------------------------------------------
template<int TM, int TN, int BK, int OUTF32, int BIAS, int GELU>
__device__ __forceinline__ void gemm_body(
    const u16* __restrict__ A, const u16* __restrict__ Bt, char* __restrict__ Cp,
    const float* __restrict__ bias, float scale, int K,
    int lda, int ldb, int ldc, int m0, int n0)
{
    constexpr int MT = TM / 32, NT = TN / 32;   // frag tiles per wave
    constexpr int CPT = BK / 8;                 // 16B chunks per LDS row
    constexpr int RPP = 2048 / BK;              // rows staged per 256-thread pass
    __shared__ alignas(16) u16 As[2][TM * BK];
    __shared__ alignas(16) u16 Bs[2][TN * BK];
    const int t = threadIdx.x, lane = t & 63, w = t >> 6;
    const int wr = (w >> 1) * (TM / 2), wc = (w & 1) * (TN / 2);
    const int fr = lane & 15, fq = lane >> 4, fk = fq * 8;
    f32x4 acc[MT][NT] = {};

    // staging: 256 threads x 16B = 4KB per pass (RPP rows x BK cols)
    const int r0a = t / CPT, c0a = (t % CPT) * 8;
    auto stageA = [&](u16* dst, int k0) {
#pragma unroll
        for (int p = 0; p < TM / RPP; p++)
            gll16(A + (long)(m0 + p * RPP + r0a) * lda + k0 + c0a, dst + p * 2048 + w * 512);
    };
    auto stageB = [&](u16* dst, int k0) {
#pragma unroll
        for (int p = 0; p < TN / RPP; p++)
            gll16(Bt + (long)(n0 + p * RPP + r0a) * ldb + k0 + c0a, dst + p * 2048 + w * 512);
    };

    stageA(As[0], 0);
    stageB(Bs[0], 0);
    int cur = 0;
    for (int k0 = 0; k0 < K; k0 += BK) {
        __syncthreads();                       // drains vmcnt -> buf[cur] ready
        if (k0 + BK < K) {
            stageA(As[cur ^ 1], k0 + BK);
            stageB(Bs[cur ^ 1], k0 + BK);
        }
        const u16* as = As[cur];
        const u16* bs = Bs[cur];
#pragma unroll
        for (int kk = 0; kk < BK; kk += 32) {
            bf16x8 af[MT], bfv[NT];
#pragma unroll
            for (int mt = 0; mt < MT; mt++) af [mt] = ld8(&as[(wr + mt * 16 + fr) * BK + kk + fk]);
#pragma unroll
            for (int nt = 0; nt < NT; nt++) bfv[nt] = ld8(&bs[(wc + nt * 16 + fr) * BK + kk + fk]);
#pragma unroll
            for (int mt = 0; mt < MT; mt++)
#pragma unroll
                for (int nt = 0; nt < NT; nt++)
                    acc[mt][nt] = __builtin_amdgcn_mfma_f32_16x16x32_bf16(af[mt], bfv[nt], acc[mt][nt], 0, 0, 0);
        }
        cur ^= 1;
    }

    // C/D layout (m89/m91): col = lane&15, row = (lane>>4)*4 + reg.
#pragma unroll
    for (int nt = 0; nt < NT; nt++) {
        const int col = n0 + wc + nt * 16 + fr;
        float bv = 0.f;
        if (BIAS) bv = bias[col];
#pragma unroll
        for (int mt = 0; mt < MT; mt++) {
            const int rbase = m0 + wr + mt * 16 + fq * 4;
#pragma unroll
            for (int r = 0; r < 4; r++) {
                float v = acc[mt][nt][r] * scale;
                if (BIAS) v += bv;
                if (GELU) v = 0.5f * v * (1.0f + erff(v * 0.70710678118654752f));
                long idx = (long)(rbase + r) * ldc + col;
                if (OUTF32) ((float*)Cp)[idx] = v;
                else        ((u16*) Cp)[idx] = f2bf(v);
            }
        }
    }
}

// ---------------------------------------------------------------------------
// General GEMM dispatch wrapper.
// SEL=0: single problem. SEL=1: y-half selects (A0,B0,C0)/(A1,B1,C1).
// LDS = 4*BK*(TM+TN) bytes; min-waves set so resident blocks fit LDS.
// ---------------------------------------------------------------------------
template<int TM, int TN, int BK, int SEL, int OUTF32, int BIAS, int GELU>
__global__ __launch_bounds__(256, ((TM + TN >= 256) ? ((BK == 64) ? 2 : 3)
                                                    : ((BK == 64) ? 3 : 4)))
void gemm_a(const u16* __restrict__ A0, const u16* __restrict__ A1,
            const u16* __restrict__ B0, const u16* __restrict__ B1,
            void* __restrict__ C0v, void* __restrict__ C1v,
            const float* __restrict__ bias,
            float scale, int K,
            int lda, int ldb, int ldc,
            long sA, long sB, long sC)
{
    int by = blockIdx.y, bz = blockIdx.z;
    const u16* A = A0; const u16* Bt = B0; char* Cp = (char*)C0v;
    if (SEL == 1) {
        int half = gridDim.y >> 1;
        if (by >= half) { A = A1; Bt = B1; Cp = (char*)C1v; by -= half; }
    }
    A += bz * sA;  Bt += bz * sB;  Cp += bz * sC * (OUTF32 ? 4 : 2);
    gemm_body<TM, TN, BK, OUTF32, BIAS, GELU>(
        A, Bt, Cp, bias, scale, K, lda, ldb, ldc, blockIdx.x * TM, by * TN);
}

// ---------------------------------------------------------------------------
// Merged q|k|vT|vcT dispatch: 1024 blocks of 128x128, K=1024, BK=32, 3/CU.
//  bid <  512: q|k  (M=4096): bx=bid&31, by=bid>>5; by<8 -> q, else k.
//  bid >= 512: vT|vcT per batch: bx=sub&7, by=(sub>>3)&7, bz=sub>>6;
//              bz<4 -> vT[b]=WsaV x xB[b]^T, else vcT[b]=WcaV x encB[b]^T.
// ---------------------------------------------------------------------------
__global__ __launch_bounds__(256, 3)
void gemm_qkv4(const u16* __restrict__ xB,  const u16* __restrict__ Wq,
               const u16* __restrict__ Wk,  u16* __restrict__ qB,
               u16* __restrict__ kB,
               const u16* __restrict__ Wv,  const u16* __restrict__ Wvc,
               const u16* __restrict__ encB,
               u16* __restrict__ vTB, u16* __restrict__ vcTB)
{
    const long M1 = (long)N_ * D_;
    int bid = blockIdx.x;
    const u16* A; const u16* Bt; u16* C; int m0, n0;
    if (bid < 512) {
        int bx = bid & 31, by = bid >> 5;
        A = xB; m0 = bx * 128;
        if (by < 8) { Bt = Wq; C = qB; n0 = by * 128; }
        else        { Bt = Wk; C = kB; n0 = (by - 8) * 128; }
    } else {
        int sub = bid - 512;
        int bx = sub & 7, by = (sub >> 3) & 7, bz = sub >> 6;
        m0 = bx * 128; n0 = by * 128;
        if (bz < 4) { A = Wv;  Bt = xB   + (long)bz * M1;       C = vTB  + (long)bz * M1; }
        else        { A = Wvc; Bt = encB + (long)(bz - 4) * M1; C = vcTB + (long)(bz - 4) * M1; }
    }
    gemm_body<128, 128, 32, 0, 0, 0>(
        A, Bt, (char*)C, nullptr, 1.f, 1024, 1024, 1024, 1024, m0, n0);
}

// ---------------------------------------------------------------------------
// 32x32-tile transpose with cast to bf16: out[c, r] = (bf16) in[r, c]
// (kept for the per-batch kcT transpose)
// ---------------------------------------------------------------------------
template<int INF32>
__global__ __launch_bounds__(256)
void transpose_cast(const void* __restrict__ in, u16* __restrict__ out,
                    int R, int C, long sIn, long sOut)
{
    __shared__ u16 tile[32][33];
    const char* ip = (const char*)in + (long)blockIdx.z * sIn * (INF32 ? 4 : 2);
    u16*        op = out + (long)blockIdx.z * sOut;
    const int bx = blockIdx.x * 32, by = blockIdx.y * 32;
    const int tx = threadIdx.x & 31, ty = threadIdx.x >> 5;
#pragma unroll
    for (int i = ty; i < 32; i += 8) {
        long idx = (long)(by + i) * C + bx + tx;
        tile[i][tx] = INF32 ? f2bf(((const float*)ip)[idx]) : ((const u16*)ip)[idx];
    }
    __syncthreads();
#pragma unroll
    for (int i = ty; i < 32; i += 8) op[(long)(bx + i) * R + by + tx] = tile[tx][i];
}

// ---------------------------------------------------------------------------
// w1 [1024,4096] and w2 [4096,1024] transposes fused: grid (128, 32, 2).
// z=0: direct tiles for w1. z=1: remap (bx,by) -> (bx>>2, by*4 + (bx&3)).
// ---------------------------------------------------------------------------
__global__ __launch_bounds__(256)
void transpose_ff(const float* __restrict__ w1, const float* __restrict__ w2,
                  u16* __restrict__ o1, u16* __restrict__ o2)
{
    __shared__ u16 tile[32][33];
    const float* in; u16* out; int R, C, bx, by;
    if (blockIdx.z == 0) {
        in = w1; out = o1; R = 1024; C = 4096;
        bx = blockIdx.x; by = blockIdx.y;                 // bx<128, by<32
    } else {
        in = w2; out = o2; R = 4096; C = 1024;
        bx = blockIdx.x >> 2; by = blockIdx.y * 4 + (blockIdx.x & 3);  // bx<32, by<128
    }
    const int x0 = bx * 32, y0 = by * 32;
    const int tx = threadIdx.x & 31, ty = threadIdx.x >> 5;
#pragma unroll
    for (int i = ty; i < 32; i += 8)
        tile[i][tx] = f2bf(in[(long)(y0 + i) * C + x0 + tx]);
    __syncthreads();
#pragma unroll
    for (int i = ty; i < 32; i += 8)
        out[(long)(x0 + i) * R + y0 + tx] = tile[tx][i];
}

// ---------------------------------------------------------------------------
// Row softmax: 1024 fp32 in -> 1024 bf16 out; one wave per row.
// Lane owns 16 contiguous cols (f32x4 loads / u16x8 stores).
// ---------------------------------------------------------------------------
__global__ __launch_bounds__(256)
void softmax_1024(const float* __restrict__ in, u16* __restrict__ out)
{
    const int lane = threadIdx.x & 63, wv = threadIdx.x >> 6;
    const long row = (long)blockIdx.x * 4 + wv;
    const float* p = in + row * 1024 + lane * 16;
    float v[16];
#pragma unroll
    for (int q = 0; q < 4; q++) {
        f32x4 a = *(const f32x4*)(p + q * 4);
#pragma unroll
        for (int e = 0; e < 4; e++) v[q * 4 + e] = a[e];
    }
    float mx = v[0];
#pragma unroll
    for (int i = 1; i < 16; i++) mx = fmaxf(mx, v[i]);
#pragma unroll
    for (int off = 32; off; off >>= 1) mx = fmaxf(mx, __shfl_xor(mx, off, 64));
    float s = 0.f;
#pragma unroll
    for (int i = 0; i < 16; i++) { v[i] = __expf(v[i] - mx); s += v[i]; }
#pragma unroll
    for (int off = 32; off; off >>= 1) s += __shfl_xor(s, off, 64);
    const float inv = 1.0f / s;
    u16* qp = out + row * 1024 + lane * 16;
#pragma unroll
    for (int q = 0; q < 2; q++) {
        u16x8 o;
#pragma unroll
        for (int e = 0; e < 8; e++) o[e] = f2bf(v[q * 8 + e] * inv);
        *(u16x8*)(qp + q * 8) = o;
    }
}

// ---------------------------------------------------------------------------
// out = LayerNorm(a + res) * g + beta ; rows of 1024; one wave per row.
// Lane owns 16 contiguous cols -> all loads/stores 16B-vectorized.
// ---------------------------------------------------------------------------
template<int AF32, int RESF32, int OUTF32>
__global__ __launch_bounds__(256)
void ln_res(const void* __restrict__ Av, const void* __restrict__ Rv,
            const float* __restrict__ g, const float* __restrict__ be,
            void* __restrict__ out)
{
    const int lane = threadIdx.x & 63, wv = threadIdx.x >> 6;
    const long row = (long)blockIdx.x * 4 + wv;
    const long off = row * 1024 + lane * 16;
    const int c0 = lane * 16;
    float v[16];
    if (AF32) {
#pragma unroll
        for (int q = 0; q < 4; q++) {
            f32x4 a = *((const f32x4*)((const float*)Av + off) + q);
#pragma unroll
            for (int e = 0; e < 4; e++) v[q * 4 + e] = a[e];
        }
    } else {
#pragma unroll
        for (int q = 0; q < 2; q++) {
            u16x8 a = *((const u16x8*)((const u16*)Av + off) + q);
#pragma unroll
            for (int e = 0; e < 8; e++) v[q * 8 + e] = bf2f(a[e]);
        }
    }
    if (RESF32) {
#pragma unroll
        for (int q = 0; q < 4; q++) {
            f32x4 a = *((const f32x4*)((const float*)Rv + off) + q);
#pragma unroll
            for (int e = 0; e < 4; e++) v[q * 4 + e] += a[e];
        }
    } else {
#pragma unroll
        for (int q = 0; q < 2; q++) {
            u16x8 a = *((const u16x8*)((const u16*)Rv + off) + q);
#pragma unroll
            for (int e = 0; e < 8; e++) v[q * 8 + e] += bf2f(a[e]);
        }
    }
    float s = 0.f;
#pragma unroll
    for (int i = 0; i < 16; i++) s += v[i];
#pragma unroll
    for (int o = 32; o; o >>= 1) s += __shfl_xor(s, o, 64);
    const float mu = s * (1.f / 1024.f);
    float s2 = 0.f;
#pragma unroll
    for (int i = 0; i < 16; i++) { float d = v[i] - mu; s2 += d * d; }
#pragma unroll
    for (int o = 32; o; o >>= 1) s2 += __shfl_xor(s2, o, 64);
    const float rs = rsqrtf(s2 * (1.f / 1024.f) + 1e-5f);

    float ov[16];
#pragma unroll
    for (int q = 0; q < 4; q++) {
        f32x4 gv = *(const f32x4*)&g[c0 + q * 4];
        f32x4 bv = *(const f32x4*)&be[c0 + q * 4];
#pragma unroll
        for (int e = 0; e < 4; e++)
            ov[q * 4 + e] = (v[q * 4 + e] - mu) * rs * gv[e] + bv[e];
    }
    if (OUTF32) {
#pragma unroll
        for (int q = 0; q < 4; q++) {
            f32x4 o;
#pragma unroll
            for (int e = 0; e < 4; e++) o[e] = ov[q * 4 + e];
            *((f32x4*)((float*)out + off) + q) = o;
        }
    } else {
#pragma unroll
        for (int q = 0; q < 2; q++) {
            u16x8 o;
#pragma unroll
            for (int e = 0; e < 8; e++) o[e] = f2bf(ov[q * 8 + e]);
            *((u16x8*)((u16*)out + off) + q) = o;
        }
    }
}

// ---------------------------------------------------------------------------
// Flash cross-attention (r8 + T5 setprio). Grid: (8 i-tiles, 16 heads, 4 b).
// One-pass softmax (|dots| <~ 8 by construction), reg-resident Q frags,
// async dbuf K/V staging.
// ---------------------------------------------------------------------------
__global__ __launch_bounds__(256, 3)
void flash_ca(const u16* __restrict__ P, const u16* __restrict__ Kc,
              const u16* __restrict__ VT, u16* __restrict__ O)
{
    __shared__ alignas(16) u16 Ks[2][64 * 64];
    __shared__ alignas(16) u16 Vs[2][64 * 64];   // [d][j]
    __shared__ alignas(16) u16 Ps[128 * 72];     // per-wave 32-row strips
    const int b = blockIdx.z, h = blockIdx.y, it = blockIdx.x;
    const long base = (long)b * N_ * D_;
    const int t = threadIdx.x, lane = t & 63, w = t >> 6;
    const int fr = lane & 15, fq = lane >> 4;

    bf16x8 qf[2][2];
#pragma unroll
    for (int mt = 0; mt < 2; mt++)
#pragma unroll
        for (int hf = 0; hf < 2; hf++)
            qf[mt][hf] = ld8(&P[base + (long)(it * 128 + w * 32 + mt * 16 + fr) * D_
                                + h * 64 + hf * 32 + fq * 8]);

    auto stageK = [&](int buf, int jt) {
#pragma unroll
        for (int p = 0; p < 2; p++)
            gll16(Kc + base + (long)(jt * 64 + p * 32 + (t >> 3)) * D_ + h * 64 + (t & 7) * 8,
                  &Ks[buf][p * 2048 + w * 512]);
    };
    auto stageV = [&](int buf, int jt) {
#pragma unroll
        for (int p = 0; p < 2; p++)
            gll16(VT + base + (long)(h * 64 + p * 32 + (t >> 3)) * D_ + jt * 64 + (t & 7) * 8,
                  &Vs[buf][p * 2048 + w * 512]);
    };

    f32x4 o[2][4] = {};
    float l_lane[2][4] = {};

    stageK(0, 0); stageV(0, 0);
    int cur = 0;
    for (int jt = 0; jt < 16; jt++) {
        __syncthreads();
        if (jt + 1 < 16) { stageK(cur ^ 1, jt + 1); stageV(cur ^ 1, jt + 1); }
        const u16* ks = Ks[cur];
        const u16* vs = Vs[cur];

        f32x4 st[2][4] = {};
        __builtin_amdgcn_s_setprio(1);
#pragma unroll
        for (int nt = 0; nt < 4; nt++) {
            bf16x8 b0 = ld8(&ks[(nt * 16 + fr) * 64 + fq * 8]);
            bf16x8 b1 = ld8(&ks[(nt * 16 + fr) * 64 + 32 + fq * 8]);
#pragma unroll
            for (int mt = 0; mt < 2; mt++) {
                st[mt][nt] = __builtin_amdgcn_mfma_f32_16x16x32_bf16(qf[mt][0], b0, st[mt][nt], 0, 0, 0);
                st[mt][nt] = __builtin_amdgcn_mfma_f32_16x16x32_bf16(qf[mt][1], b1, st[mt][nt], 0, 0, 0);
            }
        }
        __builtin_amdgcn_s_setprio(0);
#pragma unroll
        for (int mt = 0; mt < 2; mt++)
#pragma unroll
            for (int nt = 0; nt < 4; nt++)
#pragma unroll
                for (int r = 0; r < 4; r++) {
                    float e = __expf(st[mt][nt][r]);
                    l_lane[mt][r] += e;
                    Ps[(w * 32 + mt * 16 + fq * 4 + r) * 72 + nt * 16 + fr] = f2bf(e);
                }
        __asm__ volatile("s_waitcnt lgkmcnt(0)" ::: "memory");
        bf16x8 vf[4][2];
#pragma unroll
        for (int dt = 0; dt < 4; dt++) {
            vf[dt][0] = ld8(&vs[(dt * 16 + fr) * 64 + fq * 8]);
            vf[dt][1] = ld8(&vs[(dt * 16 + fr) * 64 + 32 + fq * 8]);
        }
        __builtin_amdgcn_s_setprio(1);
#pragma unroll
        for (int mt = 0; mt < 2; mt++) {
            bf16x8 p0 = ld8(&Ps[(w * 32 + mt * 16 + fr) * 72 + fq * 8]);
            bf16x8 p1 = ld8(&Ps[(w * 32 + mt * 16 + fr) * 72 + 32 + fq * 8]);
#pragma unroll
            for (int dt = 0; dt < 4; dt++) {
                o[mt][dt] = __builtin_amdgcn_mfma_f32_16x16x32_bf16(p0, vf[dt][0], o[mt][dt], 0, 0, 0);
                o[mt][dt] = __builtin_amdgcn_mfma_f32_16x16x32_bf16(p1, vf[dt][1], o[mt][dt], 0, 0, 0);
            }
        }
        __builtin_amdgcn_s_setprio(0);
        cur ^= 1;
    }
#pragma unroll
    for (int mt = 0; mt < 2; mt++)
#pragma unroll
        for (int r = 0; r < 4; r++) {
            float lt = l_lane[mt][r];
#pragma unroll
            for (int off = 1; off < 16; off <<= 1) lt += __shfl_xor(lt, off, 64);
            l_lane[mt][r] = 1.0f / lt;
        }
#pragma unroll
    for (int mt = 0; mt < 2; mt++)
#pragma unroll
        for (int dt = 0; dt < 4; dt++)
#pragma unroll
            for (int r = 0; r < 4; r++)
                O[base + (long)(it * 128 + w * 32 + mt * 16 + fq * 4 + r) * D_
                  + h * 64 + dt * 16 + fr] = f2bf(o[mt][dt][r] * l_lane[mt][r]);
}

// ---------------------------------------------------------------------------
extern "C" void kernel_launch(void* const* d_in, const int* in_sizes, int n_in,
                              void* d_out, int out_size, void* d_ws, size_t ws_size,
                              hipStream_t stream)
{
    const float* x     = (const float*)d_in[0];
    const float* enc   = (const float*)d_in[1];
    const float* sa_wq = (const float*)d_in[2];
    const float* sa_wk = (const float*)d_in[3];
    const float* sa_wv = (const float*)d_in[4];
    const float* sa_g  = (const float*)d_in[5];
    const float* sa_b  = (const float*)d_in[6];
    const float* ca_wq = (const float*)d_in[7];
    const float* ca_wk = (const float*)d_in[8];
    const float* ca_wv = (const float*)d_in[9];
    const float* ca_g  = (const float*)d_in[10];
    const float* ca_b  = (const float*)d_in[11];
    const float* w1    = (const float*)d_in[12];
    const float* b1    = (const float*)d_in[13];
    const float* w2    = (const float*)d_in[14];
    const float* b2    = (const float*)d_in[15];
    const float* ff_g  = (const float*)d_in[16];
    const float* ff_b  = (const float*)d_in[17];

    // 76 MB workspace, lifetime-overlaid (MB offsets):
    //  0- 8 xB -> attnB(attn->P) -> w2T
    //  8-16 encB -> w1T
    // 16-22 Wsa ; 22-28 Wca ; 16-32 h2F (after CA)
    // 28-36 qB_sa -> E(saln) -> flash O
    // 36-44 kB_sa -> qB(ca) -> calnB
    // 44-52 vTB -> kB(ca) ; 44-76 h1B (FF)
    // 52-60 vcTB
    // 60-76 scF (fp32) ; 60-68 kcT (CA)
    char* ws = (char*)d_ws;
    const size_t MB = 1ull << 20;
    u16*  xB    = (u16*)(ws + 0 * MB);
    u16*  attnB = (u16*)(ws + 0 * MB);
    u16*  w2T   = (u16*)(ws + 0 * MB);
    u16*  encB  = (u16*)(ws + 8 * MB);
    u16*  w1T   = (u16*)(ws + 8 * MB);
    u16*  Wsa   = (u16*)(ws + 16 * MB);   // q@+0, k@+1M, v@+2M elems
    u16*  Wca   = (u16*)(ws + 22 * MB);
    float* h2F  = (float*)(ws + 16 * MB);
    u16*  qBsa  = (u16*)(ws + 28 * MB);
    u16*  E     = (u16*)(ws + 28 * MB);   // saln, then flash O
    u16*  kBsa  = (u16*)(ws + 36 * MB);
    u16*  qBca  = (u16*)(ws + 36 * MB);
    u16*  calnB = (u16*)(ws + 36 * MB);
    u16*  vTB   = (u16*)(ws + 44 * MB);
    u16*  kBca  = (u16*)(ws + 44 * MB);
    u16*  h1B   = (u16*)(ws + 44 * MB);
    u16*  vcTB  = (u16*)(ws + 52 * MB);
    float* scF  = (float*)(ws + 60 * MB);
    u16*  kcT   = (u16*)(ws + 60 * MB);

    const dim3 blk(256, 1, 1);
    const long M1 = (long)N_ * D_;        // 1M elems, per-batch stride
    const long W1M = (long)1024 * 1024;   // weight matrix elems

    // 0) fused prep: x|enc converts + six weight transposes (one dispatch)
    prep_all<<<dim3(10240, 1, 1), blk, 0, stream>>>(
        x, enc, xB, encB, sa_wq, sa_wk, sa_wv, ca_wq, ca_wk, ca_wv, Wsa, Wca);

    // 2) q|k|vT|vcT merged: 1024 blocks of 128x128, 3 blocks/CU.
    gemm_qkv4<<<dim3(1024, 1, 1), blk, 0, stream>>>(
        xB, Wsa, Wsa + W1M, qBsa, kBsa,
        Wsa + 2 * W1M, Wca + 2 * W1M, encB, vTB, vcTB);
    // 4) scores = q k^T / 32 (fp32). grid 8x16x4 = 512, 128x64, BK=64.
    gemm_a<128,64,64,0,1,0,0><<<dim3(8, 16, 4), blk, 0, stream>>>(
        qBsa, nullptr, kBsa, nullptr, scF, nullptr, nullptr,
        0.03125f, 1024, 1024, 1024, 1024, M1, M1, M1);
    softmax_1024<<<dim3(1024, 1, 1), blk, 0, stream>>>(scF, attnB);
    // 5) sa_pre = attn @ v (fp32), BK=64
    gemm_a<128,64,64,0,1,0,0><<<dim3(8, 16, 4), blk, 0, stream>>>(
        attnB, nullptr, vTB, nullptr, scF, nullptr, nullptr,
        1.f, 1024, 1024, 1024, 1024, M1, M1, M1);
    ln_res<1,1,0><<<dim3(1024, 1, 1), blk, 0, stream>>>(scF, x, sa_g, sa_b, E);

    // 6) qc|kc fused (y-half): qc = saln @ Wq ; kc = encB @ Wk. BK=64.
    gemm_a<128,128,64,1,0,0,0><<<dim3(32, 16, 1), blk, 0, stream>>>(
        E, encB, Wca, Wca + W1M, qBca, kBca, nullptr,
        1.f, 1024, 1024, 1024, 1024, 0, 0, 0);
    // 7) kcT per batch (scF dead)
    transpose_cast<0><<<dim3(32, 32, 4), blk, 0, stream>>>(kBca, kcT, 1024, 1024, M1, M1);
    // 8) P = (qc @ kc) / 64, BK=64
    gemm_a<128,64,64,0,0,0,0><<<dim3(8, 16, 4), blk, 0, stream>>>(
        qBca, nullptr, kcT, nullptr, attnB, nullptr, nullptr,
        0.015625f, 1024, 1024, 1024, 1024, M1, M1, M1);
    // 9) flash cross-attn -> O (over saln region)
    flash_ca<<<dim3(8, 16, 4), blk, 0, stream>>>(attnB, kBca, vcTB, E);
    ln_res<0,1,0><<<dim3(1024, 1, 1), blk, 0, stream>>>(E, enc, ca_g, ca_b, calnB);

    // 10) FeedForward (w1T|w2T fused in one dispatch)
    transpose_ff<<<dim3(128, 32, 2), blk, 0, stream>>>(w1, w2, w1T, w2T);
    gemm_a<128,128,32,0,0,1,1><<<dim3(32, 32, 1), blk, 0, stream>>>(
        calnB, nullptr, w1T, nullptr, h1B, nullptr, b1,
        1.f, 1024, 1024, 1024, 4096, 0, 0, 0);
    gemm_a<128,64,64,0,1,1,0><<<dim3(32, 16, 1), blk, 0, stream>>>(
        h1B, nullptr, w2T, nullptr, h2F, nullptr, b2,
        1.f, 4096, 4096, 4096, 1024, 0, 0, 0);
    ln_res<1,0,1><<<dim3(1024, 1, 1), blk, 0, stream>>>(h2F, calnB, ff_g, ff_b, (float*)d_out);
}

// Round 4
// 467.562 us; speedup vs baseline: 1.1077x; 1.0765x over previous
//
#include <hip/hip_runtime.h>
#include <math.h>
#include <stdint.h>

// B=4, N=1024, D=1024, H=16, DH=64, MLP=4096. Inputs fp32, output fp32.
// Round 13: r3 counters: FF2 80us, MfmaUtil 16%, BANK_CONFLICT 18.9M cyc
// (~38% of dispatch time) — BK=64 row stride 128B is the G4 pathological
// case. Fix: T2 XOR swizzle via rule #21 (linear LDS dest from
// global_load_lds + inverse-permuted GLOBAL source + XOR'd ds_read):
//   slot(c,r) = c ^ (r & min(CPT-1,7)).
// BK=64 reads become conflict-free; BK=32 drops 8-way -> 2-way (free).
// Applied to all gemm_body instances and flash_ca Ks/Vs (same 128B-stride
// pathology). Everything else unchanged from r12.
typedef unsigned short u16;
typedef u16   u16x8 __attribute__((ext_vector_type(8)));
typedef __bf16 bf16x8 __attribute__((ext_vector_type(8)));
typedef float  f32x4 __attribute__((ext_vector_type(4)));

#define B_   4
#define N_   1024
#define D_   1024
#define MLP_ 4096

__device__ __forceinline__ float bf2f(u16 v) {
    unsigned u = ((unsigned)v) << 16;
    return __builtin_bit_cast(float, u);
}
__device__ __forceinline__ u16 f2bf(float f) {
    unsigned u = __builtin_bit_cast(unsigned, f);
    u += 0x7fff + ((u >> 16) & 1);   // RN-even
    return (u16)(u >> 16);
}
__device__ __forceinline__ bf16x8 ld8(const u16* p) {
    return __builtin_bit_cast(bf16x8, *(const u16x8*)p);
}
// async 16B global -> LDS (lds dest = wave-uniform base + lane*16)
__device__ __forceinline__ void gll16(const u16* g, u16* l) {
    __builtin_amdgcn_global_load_lds(
        (const __attribute__((address_space(1))) unsigned int*)g,
        (__attribute__((address_space(3))) unsigned int*)l,
        16, 0, 0);
}

// ---------------------------------------------------------------------------
// Fused prep: blocks [0,4096) convert x|enc fp32->bf16 (8 elems/thread);
// blocks [4096,10240) do the six 1024x1024 weight transposes (fp32->bf16).
// ---------------------------------------------------------------------------
__global__ __launch_bounds__(256)
void prep_all(const float* __restrict__ x, const float* __restrict__ enc,
              u16* __restrict__ xB, u16* __restrict__ encB,
              const float* __restrict__ p0, const float* __restrict__ p1,
              const float* __restrict__ p2, const float* __restrict__ p3,
              const float* __restrict__ p4, const float* __restrict__ p5,
              u16* __restrict__ Wsa, u16* __restrict__ Wca)
{
    __shared__ u16 tile[32][33];
    int bid = blockIdx.x;
    if (bid < 4096) {
        // ---- convert role ----
        const float* in = x; u16* out = xB;
        if (bid >= 2048) { in = enc; out = encB; bid -= 2048; }
        long i = (long)bid * 256 + threadIdx.x;        // < 524288 exactly
        f32x4 a = *(const f32x4*)&in[i * 8];
        f32x4 b = *(const f32x4*)&in[i * 8 + 4];
        u16x8 h;
        h[0] = f2bf(a[0]); h[1] = f2bf(a[1]); h[2] = f2bf(a[2]); h[3] = f2bf(a[3]);
        h[4] = f2bf(b[0]); h[5] = f2bf(b[1]); h[6] = f2bf(b[2]); h[7] = f2bf(b[3]);
        *(u16x8*)&out[i * 8] = h;
        return;
    }
    // ---- weight-transpose role ----
    int sub = bid - 4096;
    const int z = sub >> 10;          // 0..5
    const int t2 = sub & 1023;
    const int bx = (t2 & 31) * 32, by = (t2 >> 5) * 32;
    const float* in = p0;
    if (z == 1) in = p1;
    else if (z == 2) in = p2;
    else if (z == 3) in = p3;
    else if (z == 4) in = p4;
    else if (z == 5) in = p5;
    u16* out = (z < 3) ? Wsa + (long)z * (1 << 20) : Wca + (long)(z - 3) * (1 << 20);
    const int tx = threadIdx.x & 31, ty = threadIdx.x >> 5;
#pragma unroll
    for (int i = ty; i < 32; i += 8)
        tile[i][tx] = f2bf(in[(long)(by + i) * 1024 + bx + tx]);
    __syncthreads();
#pragma unroll
    for (int i = ty; i < 32; i += 8)
        out[(long)(bx + i) * 1024 + by + tx] = tile[tx][i];
}

// ---------------------------------------------------------------------------
// GEMM body: C[m,n] = scale*sum_k A[m,k]*Bt[n,k] (+bias)(gelu). A,Bt bf16.
// Tile TM x TN x BK, 4 waves (2x2 of TM/2 x TN/2), 16x16x32 bf16 MFMA,
// global_load_lds width=16, double-buffered K-loop (1 barrier per BK).
// T2 swizzle: LDS slot(c, r) = c ^ (r & CMASK) per 16B chunk; implemented
// as inverse-permuted global source (rule #21) + XOR'd ds_read address.
// ---------------------------------------------------------------------------
template<int TM, int TN, int BK, int OUTF32, int BIAS, int GELU>
__device__ __forceinline__ void gemm_body(
    const u16* __restrict__ A, const u16* __restrict__ Bt, char* __restrict__ Cp,
    const float* __restrict__ bias, float scale, int K,
    int lda, int ldb, int ldc, int m0, int n0)
{
    constexpr int MT = TM / 32, NT = TN / 32;   // frag tiles per wave
    constexpr int CPT = BK / 8;                 // 16B chunks per LDS row
    constexpr int RPP = 2048 / BK;              // rows staged per 256-thread pass
    constexpr int CMASK = (CPT - 1) & 7;        // swizzle mask (BK=64 -> 7, BK=32 -> 3)
    __shared__ alignas(16) u16 As[2][TM * BK];
    __shared__ alignas(16) u16 Bs[2][TN * BK];
    const int t = threadIdx.x, lane = t & 63, w = t >> 6;
    const int wr = (w >> 1) * (TM / 2), wc = (w & 1) * (TN / 2);
    const int fr = lane & 15, fq = lane >> 4;
    f32x4 acc[MT][NT] = {};

    // staging: 256 threads x 16B = 4KB per pass (RPP rows x BK cols).
    // Thread t's linear LDS dest = row (t/CPT), slot (t%CPT); load the
    // global chunk that belongs in that slot: c_src = slot ^ (row & CMASK).
    const int r0a = t / CPT;
    const int c0sw = ((t % CPT) ^ (r0a & CMASK)) * 8;
    auto stageA = [&](u16* dst, int k0) {
#pragma unroll
        for (int p = 0; p < TM / RPP; p++)
            gll16(A + (long)(m0 + p * RPP + r0a) * lda + k0 + c0sw, dst + p * 2048 + w * 512);
    };
    auto stageB = [&](u16* dst, int k0) {
#pragma unroll
        for (int p = 0; p < TN / RPP; p++)
            gll16(Bt + (long)(n0 + p * RPP + r0a) * ldb + k0 + c0sw, dst + p * 2048 + w * 512);
    };

    stageA(As[0], 0);
    stageB(Bs[0], 0);
    int cur = 0;
    for (int k0 = 0; k0 < K; k0 += BK) {
        __syncthreads();                       // drains vmcnt -> buf[cur] ready
        if (k0 + BK < K) {
            stageA(As[cur ^ 1], k0 + BK);
            stageB(Bs[cur ^ 1], k0 + BK);
        }
        const u16* as = As[cur];
        const u16* bs = Bs[cur];
#pragma unroll
        for (int kk = 0; kk < BK; kk += 32) {
            bf16x8 af[MT], bfv[NT];
#pragma unroll
            for (int mt = 0; mt < MT; mt++) {
                const int row = wr + mt * 16 + fr;
                af[mt] = ld8(&as[row * BK + ((((kk >> 3) + fq) ^ (row & CMASK)) << 3)]);
            }
#pragma unroll
            for (int nt = 0; nt < NT; nt++) {
                const int row = wc + nt * 16 + fr;
                bfv[nt] = ld8(&bs[row * BK + ((((kk >> 3) + fq) ^ (row & CMASK)) << 3)]);
            }
#pragma unroll
            for (int mt = 0; mt < MT; mt++)
#pragma unroll
                for (int nt = 0; nt < NT; nt++)
                    acc[mt][nt] = __builtin_amdgcn_mfma_f32_16x16x32_bf16(af[mt], bfv[nt], acc[mt][nt], 0, 0, 0);
        }
        cur ^= 1;
    }

    // C/D layout (m89/m91): col = lane&15, row = (lane>>4)*4 + reg.
#pragma unroll
    for (int nt = 0; nt < NT; nt++) {
        const int col = n0 + wc + nt * 16 + fr;
        float bv = 0.f;
        if (BIAS) bv = bias[col];
#pragma unroll
        for (int mt = 0; mt < MT; mt++) {
            const int rbase = m0 + wr + mt * 16 + fq * 4;
#pragma unroll
            for (int r = 0; r < 4; r++) {
                float v = acc[mt][nt][r] * scale;
                if (BIAS) v += bv;
                if (GELU) v = 0.5f * v * (1.0f + erff(v * 0.70710678118654752f));
                long idx = (long)(rbase + r) * ldc + col;
                if (OUTF32) ((float*)Cp)[idx] = v;
                else        ((u16*) Cp)[idx] = f2bf(v);
            }
        }
    }
}

// ---------------------------------------------------------------------------
// General GEMM dispatch wrapper.
// SEL=0: single problem. SEL=1: y-half selects (A0,B0,C0)/(A1,B1,C1).
// LDS = 4*BK*(TM+TN) bytes; min-waves set so resident blocks fit LDS.
// ---------------------------------------------------------------------------
template<int TM, int TN, int BK, int SEL, int OUTF32, int BIAS, int GELU>
__global__ __launch_bounds__(256, ((TM + TN >= 256) ? ((BK == 64) ? 2 : 3)
                                                    : ((BK == 64) ? 3 : 4)))
void gemm_a(const u16* __restrict__ A0, const u16* __restrict__ A1,
            const u16* __restrict__ B0, const u16* __restrict__ B1,
            void* __restrict__ C0v, void* __restrict__ C1v,
            const float* __restrict__ bias,
            float scale, int K,
            int lda, int ldb, int ldc,
            long sA, long sB, long sC)
{
    int by = blockIdx.y, bz = blockIdx.z;
    const u16* A = A0; const u16* Bt = B0; char* Cp = (char*)C0v;
    if (SEL == 1) {
        int half = gridDim.y >> 1;
        if (by >= half) { A = A1; Bt = B1; Cp = (char*)C1v; by -= half; }
    }
    A += bz * sA;  Bt += bz * sB;  Cp += bz * sC * (OUTF32 ? 4 : 2);
    gemm_body<TM, TN, BK, OUTF32, BIAS, GELU>(
        A, Bt, Cp, bias, scale, K, lda, ldb, ldc, blockIdx.x * TM, by * TN);
}

// ---------------------------------------------------------------------------
// Merged q|k|vT|vcT dispatch: 1024 blocks of 128x128, K=1024, BK=32, 3/CU.
//  bid <  512: q|k  (M=4096): bx=bid&31, by=bid>>5; by<8 -> q, else k.
//  bid >= 512: vT|vcT per batch: bx=sub&7, by=(sub>>3)&7, bz=sub>>6;
//              bz<4 -> vT[b]=WsaV x xB[b]^T, else vcT[b]=WcaV x encB[b]^T.
// ---------------------------------------------------------------------------
__global__ __launch_bounds__(256, 3)
void gemm_qkv4(const u16* __restrict__ xB,  const u16* __restrict__ Wq,
               const u16* __restrict__ Wk,  u16* __restrict__ qB,
               u16* __restrict__ kB,
               const u16* __restrict__ Wv,  const u16* __restrict__ Wvc,
               const u16* __restrict__ encB,
               u16* __restrict__ vTB, u16* __restrict__ vcTB)
{
    const long M1 = (long)N_ * D_;
    int bid = blockIdx.x;
    const u16* A; const u16* Bt; u16* C; int m0, n0;
    if (bid < 512) {
        int bx = bid & 31, by = bid >> 5;
        A = xB; m0 = bx * 128;
        if (by < 8) { Bt = Wq; C = qB; n0 = by * 128; }
        else        { Bt = Wk; C = kB; n0 = (by - 8) * 128; }
    } else {
        int sub = bid - 512;
        int bx = sub & 7, by = (sub >> 3) & 7, bz = sub >> 6;
        m0 = bx * 128; n0 = by * 128;
        if (bz < 4) { A = Wv;  Bt = xB   + (long)bz * M1;       C = vTB  + (long)bz * M1; }
        else        { A = Wvc; Bt = encB + (long)(bz - 4) * M1; C = vcTB + (long)(bz - 4) * M1; }
    }
    gemm_body<128, 128, 32, 0, 0, 0>(
        A, Bt, (char*)C, nullptr, 1.f, 1024, 1024, 1024, 1024, m0, n0);
}

// ---------------------------------------------------------------------------
// 32x32-tile transpose with cast to bf16: out[c, r] = (bf16) in[r, c]
// (kept for the per-batch kcT transpose)
// ---------------------------------------------------------------------------
template<int INF32>
__global__ __launch_bounds__(256)
void transpose_cast(const void* __restrict__ in, u16* __restrict__ out,
                    int R, int C, long sIn, long sOut)
{
    __shared__ u16 tile[32][33];
    const char* ip = (const char*)in + (long)blockIdx.z * sIn * (INF32 ? 4 : 2);
    u16*        op = out + (long)blockIdx.z * sOut;
    const int bx = blockIdx.x * 32, by = blockIdx.y * 32;
    const int tx = threadIdx.x & 31, ty = threadIdx.x >> 5;
#pragma unroll
    for (int i = ty; i < 32; i += 8) {
        long idx = (long)(by + i) * C + bx + tx;
        tile[i][tx] = INF32 ? f2bf(((const float*)ip)[idx]) : ((const u16*)ip)[idx];
    }
    __syncthreads();
#pragma unroll
    for (int i = ty; i < 32; i += 8) op[(long)(bx + i) * R + by + tx] = tile[tx][i];
}

// ---------------------------------------------------------------------------
// w1 [1024,4096] and w2 [4096,1024] transposes fused: grid (128, 32, 2).
// z=0: direct tiles for w1. z=1: remap (bx,by) -> (bx>>2, by*4 + (bx&3)).
// ---------------------------------------------------------------------------
__global__ __launch_bounds__(256)
void transpose_ff(const float* __restrict__ w1, const float* __restrict__ w2,
                  u16* __restrict__ o1, u16* __restrict__ o2)
{
    __shared__ u16 tile[32][33];
    const float* in; u16* out; int R, C, bx, by;
    if (blockIdx.z == 0) {
        in = w1; out = o1; R = 1024; C = 4096;
        bx = blockIdx.x; by = blockIdx.y;                 // bx<128, by<32
    } else {
        in = w2; out = o2; R = 4096; C = 1024;
        bx = blockIdx.x >> 2; by = blockIdx.y * 4 + (blockIdx.x & 3);  // bx<32, by<128
    }
    const int x0 = bx * 32, y0 = by * 32;
    const int tx = threadIdx.x & 31, ty = threadIdx.x >> 5;
#pragma unroll
    for (int i = ty; i < 32; i += 8)
        tile[i][tx] = f2bf(in[(long)(y0 + i) * C + x0 + tx]);
    __syncthreads();
#pragma unroll
    for (int i = ty; i < 32; i += 8)
        out[(long)(x0 + i) * R + y0 + tx] = tile[tx][i];
}

// ---------------------------------------------------------------------------
// Row softmax: 1024 fp32 in -> 1024 bf16 out; one wave per row.
// Lane owns 16 contiguous cols (f32x4 loads / u16x8 stores).
// ---------------------------------------------------------------------------
__global__ __launch_bounds__(256)
void softmax_1024(const float* __restrict__ in, u16* __restrict__ out)
{
    const int lane = threadIdx.x & 63, wv = threadIdx.x >> 6;
    const long row = (long)blockIdx.x * 4 + wv;
    const float* p = in + row * 1024 + lane * 16;
    float v[16];
#pragma unroll
    for (int q = 0; q < 4; q++) {
        f32x4 a = *(const f32x4*)(p + q * 4);
#pragma unroll
        for (int e = 0; e < 4; e++) v[q * 4 + e] = a[e];
    }
    float mx = v[0];
#pragma unroll
    for (int i = 1; i < 16; i++) mx = fmaxf(mx, v[i]);
#pragma unroll
    for (int off = 32; off; off >>= 1) mx = fmaxf(mx, __shfl_xor(mx, off, 64));
    float s = 0.f;
#pragma unroll
    for (int i = 0; i < 16; i++) { v[i] = __expf(v[i] - mx); s += v[i]; }
#pragma unroll
    for (int off = 32; off; off >>= 1) s += __shfl_xor(s, off, 64);
    const float inv = 1.0f / s;
    u16* qp = out + row * 1024 + lane * 16;
#pragma unroll
    for (int q = 0; q < 2; q++) {
        u16x8 o;
#pragma unroll
        for (int e = 0; e < 8; e++) o[e] = f2bf(v[q * 8 + e] * inv);
        *(u16x8*)(qp + q * 8) = o;
    }
}

// ---------------------------------------------------------------------------
// out = LayerNorm(a + res) * g + beta ; rows of 1024; one wave per row.
// Lane owns 16 contiguous cols -> all loads/stores 16B-vectorized.
// ---------------------------------------------------------------------------
template<int AF32, int RESF32, int OUTF32>
__global__ __launch_bounds__(256)
void ln_res(const void* __restrict__ Av, const void* __restrict__ Rv,
            const float* __restrict__ g, const float* __restrict__ be,
            void* __restrict__ out)
{
    const int lane = threadIdx.x & 63, wv = threadIdx.x >> 6;
    const long row = (long)blockIdx.x * 4 + wv;
    const long off = row * 1024 + lane * 16;
    const int c0 = lane * 16;
    float v[16];
    if (AF32) {
#pragma unroll
        for (int q = 0; q < 4; q++) {
            f32x4 a = *((const f32x4*)((const float*)Av + off) + q);
#pragma unroll
            for (int e = 0; e < 4; e++) v[q * 4 + e] = a[e];
        }
    } else {
#pragma unroll
        for (int q = 0; q < 2; q++) {
            u16x8 a = *((const u16x8*)((const u16*)Av + off) + q);
#pragma unroll
            for (int e = 0; e < 8; e++) v[q * 8 + e] = bf2f(a[e]);
        }
    }
    if (RESF32) {
#pragma unroll
        for (int q = 0; q < 4; q++) {
            f32x4 a = *((const f32x4*)((const float*)Rv + off) + q);
#pragma unroll
            for (int e = 0; e < 4; e++) v[q * 4 + e] += a[e];
        }
    } else {
#pragma unroll
        for (int q = 0; q < 2; q++) {
            u16x8 a = *((const u16x8*)((const u16*)Rv + off) + q);
#pragma unroll
            for (int e = 0; e < 8; e++) v[q * 8 + e] += bf2f(a[e]);
        }
    }
    float s = 0.f;
#pragma unroll
    for (int i = 0; i < 16; i++) s += v[i];
#pragma unroll
    for (int o = 32; o; o >>= 1) s += __shfl_xor(s, o, 64);
    const float mu = s * (1.f / 1024.f);
    float s2 = 0.f;
#pragma unroll
    for (int i = 0; i < 16; i++) { float d = v[i] - mu; s2 += d * d; }
#pragma unroll
    for (int o = 32; o; o >>= 1) s2 += __shfl_xor(s2, o, 64);
    const float rs = rsqrtf(s2 * (1.f / 1024.f) + 1e-5f);

    float ov[16];
#pragma unroll
    for (int q = 0; q < 4; q++) {
        f32x4 gv = *(const f32x4*)&g[c0 + q * 4];
        f32x4 bv = *(const f32x4*)&be[c0 + q * 4];
#pragma unroll
        for (int e = 0; e < 4; e++)
            ov[q * 4 + e] = (v[q * 4 + e] - mu) * rs * gv[e] + bv[e];
    }
    if (OUTF32) {
#pragma unroll
        for (int q = 0; q < 4; q++) {
            f32x4 o;
#pragma unroll
            for (int e = 0; e < 4; e++) o[e] = ov[q * 4 + e];
            *((f32x4*)((float*)out + off) + q) = o;
        }
    } else {
#pragma unroll
        for (int q = 0; q < 2; q++) {
            u16x8 o;
#pragma unroll
            for (int e = 0; e < 8; e++) o[e] = f2bf(ov[q * 8 + e]);
            *((u16x8*)((u16*)out + off) + q) = o;
        }
    }
}

// ---------------------------------------------------------------------------
// Flash cross-attention. Grid: (8 i-tiles, 16 heads, 4 b). T5 setprio.
// K/V LDS tiles are 64x64 (128B row stride) -> same swizzle as gemm_body:
// slot(c,r) = c ^ (r&7), via permuted global source + XOR'd ds_read.
// ---------------------------------------------------------------------------
__global__ __launch_bounds__(256, 3)
void flash_ca(const u16* __restrict__ P, const u16* __restrict__ Kc,
              const u16* __restrict__ VT, u16* __restrict__ O)
{
    __shared__ alignas(16) u16 Ks[2][64 * 64];
    __shared__ alignas(16) u16 Vs[2][64 * 64];   // [d][j]
    __shared__ alignas(16) u16 Ps[128 * 72];     // per-wave 32-row strips
    const int b = blockIdx.z, h = blockIdx.y, it = blockIdx.x;
    const long base = (long)b * N_ * D_;
    const int t = threadIdx.x, lane = t & 63, w = t >> 6;
    const int fr = lane & 15, fq = lane >> 4;

    bf16x8 qf[2][2];
#pragma unroll
    for (int mt = 0; mt < 2; mt++)
#pragma unroll
        for (int hf = 0; hf < 2; hf++)
            qf[mt][hf] = ld8(&P[base + (long)(it * 128 + w * 32 + mt * 16 + fr) * D_
                                + h * 64 + hf * 32 + fq * 8]);

    // staging: thread t -> row (t>>3), dest slot (t&7); global chunk = slot ^ (row&7)
    const int svr = t >> 3, svc = ((t & 7) ^ (svr & 7)) * 8;
    auto stageK = [&](int buf, int jt) {
#pragma unroll
        for (int p = 0; p < 2; p++)
            gll16(Kc + base + (long)(jt * 64 + p * 32 + svr) * D_ + h * 64 + svc,
                  &Ks[buf][p * 2048 + w * 512]);
    };
    auto stageV = [&](int buf, int jt) {
#pragma unroll
        for (int p = 0; p < 2; p++)
            gll16(VT + base + (long)(h * 64 + p * 32 + svr) * D_ + jt * 64 + svc,
                  &Vs[buf][p * 2048 + w * 512]);
    };

    f32x4 o[2][4] = {};
    float l_lane[2][4] = {};

    stageK(0, 0); stageV(0, 0);
    int cur = 0;
    for (int jt = 0; jt < 16; jt++) {
        __syncthreads();
        if (jt + 1 < 16) { stageK(cur ^ 1, jt + 1); stageV(cur ^ 1, jt + 1); }
        const u16* ks = Ks[cur];
        const u16* vs = Vs[cur];

        f32x4 st[2][4] = {};
        __builtin_amdgcn_s_setprio(1);
#pragma unroll
        for (int nt = 0; nt < 4; nt++) {
            const int row = nt * 16 + fr;
            bf16x8 b0 = ld8(&ks[row * 64 + ((fq ^ (row & 7)) << 3)]);
            bf16x8 b1 = ld8(&ks[row * 64 + (((fq + 4) ^ (row & 7)) << 3)]);
#pragma unroll
            for (int mt = 0; mt < 2; mt++) {
                st[mt][nt] = __builtin_amdgcn_mfma_f32_16x16x32_bf16(qf[mt][0], b0, st[mt][nt], 0, 0, 0);
                st[mt][nt] = __builtin_amdgcn_mfma_f32_16x16x32_bf16(qf[mt][1], b1, st[mt][nt], 0, 0, 0);
            }
        }
        __builtin_amdgcn_s_setprio(0);
#pragma unroll
        for (int mt = 0; mt < 2; mt++)
#pragma unroll
            for (int nt = 0; nt < 4; nt++)
#pragma unroll
                for (int r = 0; r < 4; r++) {
                    float e = __expf(st[mt][nt][r]);
                    l_lane[mt][r] += e;
                    Ps[(w * 32 + mt * 16 + fq * 4 + r) * 72 + nt * 16 + fr] = f2bf(e);
                }
        __asm__ volatile("s_waitcnt lgkmcnt(0)" ::: "memory");
        bf16x8 vf[4][2];
#pragma unroll
        for (int dt = 0; dt < 4; dt++) {
            const int row = dt * 16 + fr;
            vf[dt][0] = ld8(&vs[row * 64 + ((fq ^ (row & 7)) << 3)]);
            vf[dt][1] = ld8(&vs[row * 64 + (((fq + 4) ^ (row & 7)) << 3)]);
        }
        __builtin_amdgcn_s_setprio(1);
#pragma unroll
        for (int mt = 0; mt < 2; mt++) {
            bf16x8 p0 = ld8(&Ps[(w * 32 + mt * 16 + fr) * 72 + fq * 8]);
            bf16x8 p1 = ld8(&Ps[(w * 32 + mt * 16 + fr) * 72 + 32 + fq * 8]);
#pragma unroll
            for (int dt = 0; dt < 4; dt++) {
                o[mt][dt] = __builtin_amdgcn_mfma_f32_16x16x32_bf16(p0, vf[dt][0], o[mt][dt], 0, 0, 0);
                o[mt][dt] = __builtin_amdgcn_mfma_f32_16x16x32_bf16(p1, vf[dt][1], o[mt][dt], 0, 0, 0);
            }
        }
        __builtin_amdgcn_s_setprio(0);
        cur ^= 1;
    }
#pragma unroll
    for (int mt = 0; mt < 2; mt++)
#pragma unroll
        for (int r = 0; r < 4; r++) {
            float lt = l_lane[mt][r];
#pragma unroll
            for (int off = 1; off < 16; off <<= 1) lt += __shfl_xor(lt, off, 64);
            l_lane[mt][r] = 1.0f / lt;
        }
#pragma unroll
    for (int mt = 0; mt < 2; mt++)
#pragma unroll
        for (int dt = 0; dt < 4; dt++)
#pragma unroll
            for (int r = 0; r < 4; r++)
                O[base + (long)(it * 128 + w * 32 + mt * 16 + fq * 4 + r) * D_
                  + h * 64 + dt * 16 + fr] = f2bf(o[mt][dt][r] * l_lane[mt][r]);
}

// ---------------------------------------------------------------------------
extern "C" void kernel_launch(void* const* d_in, const int* in_sizes, int n_in,
                              void* d_out, int out_size, void* d_ws, size_t ws_size,
                              hipStream_t stream)
{
    const float* x     = (const float*)d_in[0];
    const float* enc   = (const float*)d_in[1];
    const float* sa_wq = (const float*)d_in[2];
    const float* sa_wk = (const float*)d_in[3];
    const float* sa_wv = (const float*)d_in[4];
    const float* sa_g  = (const float*)d_in[5];
    const float* sa_b  = (const float*)d_in[6];
    const float* ca_wq = (const float*)d_in[7];
    const float* ca_wk = (const float*)d_in[8];
    const float* ca_wv = (const float*)d_in[9];
    const float* ca_g  = (const float*)d_in[10];
    const float* ca_b  = (const float*)d_in[11];
    const float* w1    = (const float*)d_in[12];
    const float* b1    = (const float*)d_in[13];
    const float* w2    = (const float*)d_in[14];
    const float* b2    = (const float*)d_in[15];
    const float* ff_g  = (const float*)d_in[16];
    const float* ff_b  = (const float*)d_in[17];

    // 76 MB workspace, lifetime-overlaid (MB offsets):
    //  0- 8 xB -> attnB(attn->P) -> w2T
    //  8-16 encB -> w1T
    // 16-22 Wsa ; 22-28 Wca ; 16-32 h2F (after CA)
    // 28-36 qB_sa -> E(saln) -> flash O
    // 36-44 kB_sa -> qB(ca) -> calnB
    // 44-52 vTB -> kB(ca) ; 44-76 h1B (FF)
    // 52-60 vcTB
    // 60-76 scF (fp32) ; 60-68 kcT (CA)
    char* ws = (char*)d_ws;
    const size_t MB = 1ull << 20;
    u16*  xB    = (u16*)(ws + 0 * MB);
    u16*  attnB = (u16*)(ws + 0 * MB);
    u16*  w2T   = (u16*)(ws + 0 * MB);
    u16*  encB  = (u16*)(ws + 8 * MB);
    u16*  w1T   = (u16*)(ws + 8 * MB);
    u16*  Wsa   = (u16*)(ws + 16 * MB);   // q@+0, k@+1M, v@+2M elems
    u16*  Wca   = (u16*)(ws + 22 * MB);
    float* h2F  = (float*)(ws + 16 * MB);
    u16*  qBsa  = (u16*)(ws + 28 * MB);
    u16*  E     = (u16*)(ws + 28 * MB);   // saln, then flash O
    u16*  kBsa  = (u16*)(ws + 36 * MB);
    u16*  qBca  = (u16*)(ws + 36 * MB);
    u16*  calnB = (u16*)(ws + 36 * MB);
    u16*  vTB   = (u16*)(ws + 44 * MB);
    u16*  kBca  = (u16*)(ws + 44 * MB);
    u16*  h1B   = (u16*)(ws + 44 * MB);
    u16*  vcTB  = (u16*)(ws + 52 * MB);
    float* scF  = (float*)(ws + 60 * MB);
    u16*  kcT   = (u16*)(ws + 60 * MB);

    const dim3 blk(256, 1, 1);
    const long M1 = (long)N_ * D_;        // 1M elems, per-batch stride
    const long W1M = (long)1024 * 1024;   // weight matrix elems

    // 0) fused prep: x|enc converts + six weight transposes (one dispatch)
    prep_all<<<dim3(10240, 1, 1), blk, 0, stream>>>(
        x, enc, xB, encB, sa_wq, sa_wk, sa_wv, ca_wq, ca_wk, ca_wv, Wsa, Wca);

    // 2) q|k|vT|vcT merged: 1024 blocks of 128x128, 3 blocks/CU.
    gemm_qkv4<<<dim3(1024, 1, 1), blk, 0, stream>>>(
        xB, Wsa, Wsa + W1M, qBsa, kBsa,
        Wsa + 2 * W1M, Wca + 2 * W1M, encB, vTB, vcTB);
    // 4) scores = q k^T / 32 (fp32). grid 8x16x4 = 512, 128x64, BK=64.
    gemm_a<128,64,64,0,1,0,0><<<dim3(8, 16, 4), blk, 0, stream>>>(
        qBsa, nullptr, kBsa, nullptr, scF, nullptr, nullptr,
        0.03125f, 1024, 1024, 1024, 1024, M1, M1, M1);
    softmax_1024<<<dim3(1024, 1, 1), blk, 0, stream>>>(scF, attnB);
    // 5) sa_pre = attn @ v (fp32), BK=64
    gemm_a<128,64,64,0,1,0,0><<<dim3(8, 16, 4), blk, 0, stream>>>(
        attnB, nullptr, vTB, nullptr, scF, nullptr, nullptr,
        1.f, 1024, 1024, 1024, 1024, M1, M1, M1);
    ln_res<1,1,0><<<dim3(1024, 1, 1), blk, 0, stream>>>(scF, x, sa_g, sa_b, E);

    // 6) qc|kc fused (y-half): qc = saln @ Wq ; kc = encB @ Wk. BK=64.
    gemm_a<128,128,64,1,0,0,0><<<dim3(32, 16, 1), blk, 0, stream>>>(
        E, encB, Wca, Wca + W1M, qBca, kBca, nullptr,
        1.f, 1024, 1024, 1024, 1024, 0, 0, 0);
    // 7) kcT per batch (scF dead)
    transpose_cast<0><<<dim3(32, 32, 4), blk, 0, stream>>>(kBca, kcT, 1024, 1024, M1, M1);
    // 8) P = (qc @ kc) / 64, BK=64
    gemm_a<128,64,64,0,0,0,0><<<dim3(8, 16, 4), blk, 0, stream>>>(
        qBca, nullptr, kcT, nullptr, attnB, nullptr, nullptr,
        0.015625f, 1024, 1024, 1024, 1024, M1, M1, M1);
    // 9) flash cross-attn -> O (over saln region)
    flash_ca<<<dim3(8, 16, 4), blk, 0, stream>>>(attnB, kBca, vcTB, E);
    ln_res<0,1,0><<<dim3(1024, 1, 1), blk, 0, stream>>>(E, enc, ca_g, ca_b, calnB);

    // 10) FeedForward (w1T|w2T fused in one dispatch)
    transpose_ff<<<dim3(128, 32, 2), blk, 0, stream>>>(w1, w2, w1T, w2T);
    gemm_a<128,128,32,0,0,1,1><<<dim3(32, 32, 1), blk, 0, stream>>>(
        calnB, nullptr, w1T, nullptr, h1B, nullptr, b1,
        1.f, 1024, 1024, 1024, 4096, 0, 0, 0);
    gemm_a<128,64,64,0,1,1,0><<<dim3(32, 16, 1), blk, 0, stream>>>(
        h1B, nullptr, w2T, nullptr, h2F, nullptr, b2,
        1.f, 4096, 4096, 4096, 1024, 0, 0, 0);
    ln_res<1,0,1><<<dim3(1024, 1, 1), blk, 0, stream>>>(h2F, calnB, ff_g, ff_b, (float*)d_out);
}

// Round 8
// 460.266 us; speedup vs baseline: 1.1253x; 1.0159x over previous
//
#include <hip/hip_runtime.h>
#include <math.h>
#include <stdint.h>

// B=4, N=1024, D=1024, H=16, DH=64, MLP=4096. Inputs fp32, output fp32.
// Round 17: resubmission of r15/r16 UNCHANGED (two infra failures in a row —
// kernel never measured; carries the unverified gelu 1/sqrt(2) fix, so no
// new deltas are stacked until it validates).
// r15 = r14 package + gelu fix:
// (1) Fast erf (A&S 7.1.26, |err|<1.5e-7) in GELU epilogue, CORRECT
//     argument scaling ax = |v|*0.70710678.
// (2) min-waves 4 for BK=32 128x128 kernels (FF1, qkv4) -> 4 blk/CU.
// Swizzle (r13), BK=64 set, merged dispatches unchanged.
typedef unsigned short u16;
typedef u16   u16x8 __attribute__((ext_vector_type(8)));
typedef __bf16 bf16x8 __attribute__((ext_vector_type(8)));
typedef float  f32x4 __attribute__((ext_vector_type(4)));

#define B_   4
#define N_   1024
#define D_   1024
#define MLP_ 4096

__device__ __forceinline__ float bf2f(u16 v) {
    unsigned u = ((unsigned)v) << 16;
    return __builtin_bit_cast(float, u);
}
__device__ __forceinline__ u16 f2bf(float f) {
    unsigned u = __builtin_bit_cast(unsigned, f);
    u += 0x7fff + ((u >> 16) & 1);   // RN-even
    return (u16)(u >> 16);
}
__device__ __forceinline__ bf16x8 ld8(const u16* p) {
    return __builtin_bit_cast(bf16x8, *(const u16x8*)p);
}
// async 16B global -> LDS (lds dest = wave-uniform base + lane*16)
__device__ __forceinline__ void gll16(const u16* g, u16* l) {
    __builtin_amdgcn_global_load_lds(
        (const __attribute__((address_space(1))) unsigned int*)g,
        (__attribute__((address_space(3))) unsigned int*)l,
        16, 0, 0);
}
// GELU(v) = 0.5 v (1 + erf(v/sqrt2)); erf via A&S 7.1.26 (|err|<1.5e-7).
__device__ __forceinline__ float gelu_f(float v) {
    float xs = v * 0.70710678118654752f;     // erf argument
    float ax = fabsf(xs);
    float t  = __builtin_amdgcn_rcpf(fmaf(0.3275911f, ax, 1.0f));
    float p  = fmaf(1.061405429f, t, -1.453152027f);
    p = fmaf(p, t, 1.421413741f);
    p = fmaf(p, t, -0.284496736f);
    p = fmaf(p, t, 0.254829592f);
    p *= t;
    float e = __expf(-ax * ax);
    float er = 1.0f - p * e;                 // erf(|xs|)
    er = copysignf(er, xs);
    return 0.5f * v * (1.0f + er);
}

// ---------------------------------------------------------------------------
// Fused prep: blocks [0,4096) convert x|enc fp32->bf16 (8 elems/thread);
// blocks [4096,10240) do the six 1024x1024 weight transposes (fp32->bf16).
// ---------------------------------------------------------------------------
__global__ __launch_bounds__(256)
void prep_all(const float* __restrict__ x, const float* __restrict__ enc,
              u16* __restrict__ xB, u16* __restrict__ encB,
              const float* __restrict__ p0, const float* __restrict__ p1,
              const float* __restrict__ p2, const float* __restrict__ p3,
              const float* __restrict__ p4, const float* __restrict__ p5,
              u16* __restrict__ Wsa, u16* __restrict__ Wca)
{
    __shared__ u16 tile[32][33];
    int bid = blockIdx.x;
    if (bid < 4096) {
        // ---- convert role ----
        const float* in = x; u16* out = xB;
        if (bid >= 2048) { in = enc; out = encB; bid -= 2048; }
        long i = (long)bid * 256 + threadIdx.x;        // < 524288 exactly
        f32x4 a = *(const f32x4*)&in[i * 8];
        f32x4 b = *(const f32x4*)&in[i * 8 + 4];
        u16x8 h;
        h[0] = f2bf(a[0]); h[1] = f2bf(a[1]); h[2] = f2bf(a[2]); h[3] = f2bf(a[3]);
        h[4] = f2bf(b[0]); h[5] = f2bf(b[1]); h[6] = f2bf(b[2]); h[7] = f2bf(b[3]);
        *(u16x8*)&out[i * 8] = h;
        return;
    }
    // ---- weight-transpose role ----
    int sub = bid - 4096;
    const int z = sub >> 10;          // 0..5
    const int t2 = sub & 1023;
    const int bx = (t2 & 31) * 32, by = (t2 >> 5) * 32;
    const float* in = p0;
    if (z == 1) in = p1;
    else if (z == 2) in = p2;
    else if (z == 3) in = p3;
    else if (z == 4) in = p4;
    else if (z == 5) in = p5;
    u16* out = (z < 3) ? Wsa + (long)z * (1 << 20) : Wca + (long)(z - 3) * (1 << 20);
    const int tx = threadIdx.x & 31, ty = threadIdx.x >> 5;
#pragma unroll
    for (int i = ty; i < 32; i += 8)
        tile[i][tx] = f2bf(in[(long)(by + i) * 1024 + bx + tx]);
    __syncthreads();
#pragma unroll
    for (int i = ty; i < 32; i += 8)
        out[(long)(bx + i) * 1024 + by + tx] = tile[tx][i];
}

// ---------------------------------------------------------------------------
// GEMM body: C[m,n] = scale*sum_k A[m,k]*Bt[n,k] (+bias)(gelu). A,Bt bf16.
// Tile TM x TN x BK, 4 waves (2x2 of TM/2 x TN/2), 16x16x32 bf16 MFMA,
// global_load_lds width=16, double-buffered K-loop (1 barrier per BK).
// T2 swizzle: LDS slot(c, r) = c ^ (r & CMASK) per 16B chunk; implemented
// as inverse-permuted global source (rule #21) + XOR'd ds_read address.
// ---------------------------------------------------------------------------
template<int TM, int TN, int BK, int OUTF32, int BIAS, int GELU>
__device__ __forceinline__ void gemm_body(
    const u16* __restrict__ A, const u16* __restrict__ Bt, char* __restrict__ Cp,
    const float* __restrict__ bias, float scale, int K,
    int lda, int ldb, int ldc, int m0, int n0)
{
    constexpr int MT = TM / 32, NT = TN / 32;   // frag tiles per wave
    constexpr int CPT = BK / 8;                 // 16B chunks per LDS row
    constexpr int RPP = 2048 / BK;              // rows staged per 256-thread pass
    constexpr int CMASK = (CPT - 1) & 7;        // swizzle mask (BK=64 -> 7, BK=32 -> 3)
    __shared__ alignas(16) u16 As[2][TM * BK];
    __shared__ alignas(16) u16 Bs[2][TN * BK];
    const int t = threadIdx.x, lane = t & 63, w = t >> 6;
    const int wr = (w >> 1) * (TM / 2), wc = (w & 1) * (TN / 2);
    const int fr = lane & 15, fq = lane >> 4;
    f32x4 acc[MT][NT] = {};

    // staging: 256 threads x 16B = 4KB per pass (RPP rows x BK cols).
    // Thread t's linear LDS dest = row (t/CPT), slot (t%CPT); load the
    // global chunk that belongs in that slot: c_src = slot ^ (row & CMASK).
    const int r0a = t / CPT;
    const int c0sw = ((t % CPT) ^ (r0a & CMASK)) * 8;
    auto stageA = [&](u16* dst, int k0) {
#pragma unroll
        for (int p = 0; p < TM / RPP; p++)
            gll16(A + (long)(m0 + p * RPP + r0a) * lda + k0 + c0sw, dst + p * 2048 + w * 512);
    };
    auto stageB = [&](u16* dst, int k0) {
#pragma unroll
        for (int p = 0; p < TN / RPP; p++)
            gll16(Bt + (long)(n0 + p * RPP + r0a) * ldb + k0 + c0sw, dst + p * 2048 + w * 512);
    };

    stageA(As[0], 0);
    stageB(Bs[0], 0);
    int cur = 0;
    for (int k0 = 0; k0 < K; k0 += BK) {
        __syncthreads();                       // drains vmcnt -> buf[cur] ready
        if (k0 + BK < K) {
            stageA(As[cur ^ 1], k0 + BK);
            stageB(Bs[cur ^ 1], k0 + BK);
        }
        const u16* as = As[cur];
        const u16* bs = Bs[cur];
#pragma unroll
        for (int kk = 0; kk < BK; kk += 32) {
            bf16x8 af[MT], bfv[NT];
#pragma unroll
            for (int mt = 0; mt < MT; mt++) {
                const int row = wr + mt * 16 + fr;
                af[mt] = ld8(&as[row * BK + ((((kk >> 3) + fq) ^ (row & CMASK)) << 3)]);
            }
#pragma unroll
            for (int nt = 0; nt < NT; nt++) {
                const int row = wc + nt * 16 + fr;
                bfv[nt] = ld8(&bs[row * BK + ((((kk >> 3) + fq) ^ (row & CMASK)) << 3)]);
            }
#pragma unroll
            for (int mt = 0; mt < MT; mt++)
#pragma unroll
                for (int nt = 0; nt < NT; nt++)
                    acc[mt][nt] = __builtin_amdgcn_mfma_f32_16x16x32_bf16(af[mt], bfv[nt], acc[mt][nt], 0, 0, 0);
        }
        cur ^= 1;
    }

    // C/D layout (m89/m91): col = lane&15, row = (lane>>4)*4 + reg.
#pragma unroll
    for (int nt = 0; nt < NT; nt++) {
        const int col = n0 + wc + nt * 16 + fr;
        float bv = 0.f;
        if (BIAS) bv = bias[col];
#pragma unroll
        for (int mt = 0; mt < MT; mt++) {
            const int rbase = m0 + wr + mt * 16 + fq * 4;
#pragma unroll
            for (int r = 0; r < 4; r++) {
                float v = acc[mt][nt][r] * scale;
                if (BIAS) v += bv;
                if (GELU) v = gelu_f(v);
                long idx = (long)(rbase + r) * ldc + col;
                if (OUTF32) ((float*)Cp)[idx] = v;
                else        ((u16*) Cp)[idx] = f2bf(v);
            }
        }
    }
}

// ---------------------------------------------------------------------------
// General GEMM dispatch wrapper.
// SEL=0: single problem. SEL=1: y-half selects (A0,B0,C0)/(A1,B1,C1).
// LDS = 4*BK*(TM+TN) bytes. min-waves: 32KB -> 4 blk/CU, 48KB -> 3, 64KB -> 2.
// ---------------------------------------------------------------------------
template<int TM, int TN, int BK, int SEL, int OUTF32, int BIAS, int GELU>
__global__ __launch_bounds__(256, ((TM + TN >= 256) ? ((BK == 64) ? 2 : 4)
                                                    : ((BK == 64) ? 3 : 4)))
void gemm_a(const u16* __restrict__ A0, const u16* __restrict__ A1,
            const u16* __restrict__ B0, const u16* __restrict__ B1,
            void* __restrict__ C0v, void* __restrict__ C1v,
            const float* __restrict__ bias,
            float scale, int K,
            int lda, int ldb, int ldc,
            long sA, long sB, long sC)
{
    int by = blockIdx.y, bz = blockIdx.z;
    const u16* A = A0; const u16* Bt = B0; char* Cp = (char*)C0v;
    if (SEL == 1) {
        int half = gridDim.y >> 1;
        if (by >= half) { A = A1; Bt = B1; Cp = (char*)C1v; by -= half; }
    }
    A += bz * sA;  Bt += bz * sB;  Cp += bz * sC * (OUTF32 ? 4 : 2);
    gemm_body<TM, TN, BK, OUTF32, BIAS, GELU>(
        A, Bt, Cp, bias, scale, K, lda, ldb, ldc, blockIdx.x * TM, by * TN);
}

// ---------------------------------------------------------------------------
// Merged q|k|vT|vcT dispatch: 1024 blocks of 128x128, K=1024, BK=32, 4/CU.
//  bid <  512: q|k  (M=4096): bx=bid&31, by=bid>>5; by<8 -> q, else k.
//  bid >= 512: vT|vcT per batch: bx=sub&7, by=(sub>>3)&7, bz=sub>>6;
//              bz<4 -> vT[b]=WsaV x xB[b]^T, else vcT[b]=WcaV x encB[b]^T.
// ---------------------------------------------------------------------------
__global__ __launch_bounds__(256, 4)
void gemm_qkv4(const u16* __restrict__ xB,  const u16* __restrict__ Wq,
               const u16* __restrict__ Wk,  u16* __restrict__ qB,
               u16* __restrict__ kB,
               const u16* __restrict__ Wv,  const u16* __restrict__ Wvc,
               const u16* __restrict__ encB,
               u16* __restrict__ vTB, u16* __restrict__ vcTB)
{
    const long M1 = (long)N_ * D_;
    int bid = blockIdx.x;
    const u16* A; const u16* Bt; u16* C; int m0, n0;
    if (bid < 512) {
        int bx = bid & 31, by = bid >> 5;
        A = xB; m0 = bx * 128;
        if (by < 8) { Bt = Wq; C = qB; n0 = by * 128; }
        else        { Bt = Wk; C = kB; n0 = (by - 8) * 128; }
    } else {
        int sub = bid - 512;
        int bx = sub & 7, by = (sub >> 3) & 7, bz = sub >> 6;
        m0 = bx * 128; n0 = by * 128;
        if (bz < 4) { A = Wv;  Bt = xB   + (long)bz * M1;       C = vTB  + (long)bz * M1; }
        else        { A = Wvc; Bt = encB + (long)(bz - 4) * M1; C = vcTB + (long)(bz - 4) * M1; }
    }
    gemm_body<128, 128, 32, 0, 0, 0>(
        A, Bt, (char*)C, nullptr, 1.f, 1024, 1024, 1024, 1024, m0, n0);
}

// ---------------------------------------------------------------------------
// 32x32-tile transpose with cast to bf16: out[c, r] = (bf16) in[r, c]
// (kept for the per-batch kcT transpose)
// ---------------------------------------------------------------------------
template<int INF32>
__global__ __launch_bounds__(256)
void transpose_cast(const void* __restrict__ in, u16* __restrict__ out,
                    int R, int C, long sIn, long sOut)
{
    __shared__ u16 tile[32][33];
    const char* ip = (const char*)in + (long)blockIdx.z * sIn * (INF32 ? 4 : 2);
    u16*        op = out + (long)blockIdx.z * sOut;
    const int bx = blockIdx.x * 32, by = blockIdx.y * 32;
    const int tx = threadIdx.x & 31, ty = threadIdx.x >> 5;
#pragma unroll
    for (int i = ty; i < 32; i += 8) {
        long idx = (long)(by + i) * C + bx + tx;
        tile[i][tx] = INF32 ? f2bf(((const float*)ip)[idx]) : ((const u16*)ip)[idx];
    }
    __syncthreads();
#pragma unroll
    for (int i = ty; i < 32; i += 8) op[(long)(bx + i) * R + by + tx] = tile[tx][i];
}

// ---------------------------------------------------------------------------
// w1 [1024,4096] and w2 [4096,1024] transposes fused: grid (128, 32, 2).
// z=0: direct tiles for w1. z=1: remap (bx,by) -> (bx>>2, by*4 + (bx&3)).
// ---------------------------------------------------------------------------
__global__ __launch_bounds__(256)
void transpose_ff(const float* __restrict__ w1, const float* __restrict__ w2,
                  u16* __restrict__ o1, u16* __restrict__ o2)
{
    __shared__ u16 tile[32][33];
    const float* in; u16* out; int R, C, bx, by;
    if (blockIdx.z == 0) {
        in = w1; out = o1; R = 1024; C = 4096;
        bx = blockIdx.x; by = blockIdx.y;                 // bx<128, by<32
    } else {
        in = w2; out = o2; R = 4096; C = 1024;
        bx = blockIdx.x >> 2; by = blockIdx.y * 4 + (blockIdx.x & 3);  // bx<32, by<128
    }
    const int x0 = bx * 32, y0 = by * 32;
    const int tx = threadIdx.x & 31, ty = threadIdx.x >> 5;
#pragma unroll
    for (int i = ty; i < 32; i += 8)
        tile[i][tx] = f2bf(in[(long)(y0 + i) * C + x0 + tx]);
    __syncthreads();
#pragma unroll
    for (int i = ty; i < 32; i += 8)
        out[(long)(x0 + i) * R + y0 + tx] = tile[tx][i];
}

// ---------------------------------------------------------------------------
// Row softmax: 1024 fp32 in -> 1024 bf16 out; one wave per row.
// Lane owns 16 contiguous cols (f32x4 loads / u16x8 stores).
// ---------------------------------------------------------------------------
__global__ __launch_bounds__(256)
void softmax_1024(const float* __restrict__ in, u16* __restrict__ out)
{
    const int lane = threadIdx.x & 63, wv = threadIdx.x >> 6;
    const long row = (long)blockIdx.x * 4 + wv;
    const float* p = in + row * 1024 + lane * 16;
    float v[16];
#pragma unroll
    for (int q = 0; q < 4; q++) {
        f32x4 a = *(const f32x4*)(p + q * 4);
#pragma unroll
        for (int e = 0; e < 4; e++) v[q * 4 + e] = a[e];
    }
    float mx = v[0];
#pragma unroll
    for (int i = 1; i < 16; i++) mx = fmaxf(mx, v[i]);
#pragma unroll
    for (int off = 32; off; off >>= 1) mx = fmaxf(mx, __shfl_xor(mx, off, 64));
    float s = 0.f;
#pragma unroll
    for (int i = 0; i < 16; i++) { v[i] = __expf(v[i] - mx); s += v[i]; }
#pragma unroll
    for (int off = 32; off; off >>= 1) s += __shfl_xor(s, off, 64);
    const float inv = 1.0f / s;
    u16* qp = out + row * 1024 + lane * 16;
#pragma unroll
    for (int q = 0; q < 2; q++) {
        u16x8 o;
#pragma unroll
        for (int e = 0; e < 8; e++) o[e] = f2bf(v[q * 8 + e] * inv);
        *(u16x8*)(qp + q * 8) = o;
    }
}

// ---------------------------------------------------------------------------
// out = LayerNorm(a + res) * g + beta ; rows of 1024; one wave per row.
// Lane owns 16 contiguous cols -> all loads/stores 16B-vectorized.
// ---------------------------------------------------------------------------
template<int AF32, int RESF32, int OUTF32>
__global__ __launch_bounds__(256)
void ln_res(const void* __restrict__ Av, const void* __restrict__ Rv,
            const float* __restrict__ g, const float* __restrict__ be,
            void* __restrict__ out)
{
    const int lane = threadIdx.x & 63, wv = threadIdx.x >> 6;
    const long row = (long)blockIdx.x * 4 + wv;
    const long off = row * 1024 + lane * 16;
    const int c0 = lane * 16;
    float v[16];
    if (AF32) {
#pragma unroll
        for (int q = 0; q < 4; q++) {
            f32x4 a = *((const f32x4*)((const float*)Av + off) + q);
#pragma unroll
            for (int e = 0; e < 4; e++) v[q * 4 + e] = a[e];
        }
    } else {
#pragma unroll
        for (int q = 0; q < 2; q++) {
            u16x8 a = *((const u16x8*)((const u16*)Av + off) + q);
#pragma unroll
            for (int e = 0; e < 8; e++) v[q * 8 + e] = bf2f(a[e]);
        }
    }
    if (RESF32) {
#pragma unroll
        for (int q = 0; q < 4; q++) {
            f32x4 a = *((const f32x4*)((const float*)Rv + off) + q);
#pragma unroll
            for (int e = 0; e < 4; e++) v[q * 4 + e] += a[e];
        }
    } else {
#pragma unroll
        for (int q = 0; q < 2; q++) {
            u16x8 a = *((const u16x8*)((const u16*)Rv + off) + q);
#pragma unroll
            for (int e = 0; e < 8; e++) v[q * 8 + e] += bf2f(a[e]);
        }
    }
    float s = 0.f;
#pragma unroll
    for (int i = 0; i < 16; i++) s += v[i];
#pragma unroll
    for (int o = 32; o; o >>= 1) s += __shfl_xor(s, o, 64);
    const float mu = s * (1.f / 1024.f);
    float s2 = 0.f;
#pragma unroll
    for (int i = 0; i < 16; i++) { float d = v[i] - mu; s2 += d * d; }
#pragma unroll
    for (int o = 32; o; o >>= 1) s2 += __shfl_xor(s2, o, 64);
    const float rs = rsqrtf(s2 * (1.f / 1024.f) + 1e-5f);

    float ov[16];
#pragma unroll
    for (int q = 0; q < 4; q++) {
        f32x4 gv = *(const f32x4*)&g[c0 + q * 4];
        f32x4 bv = *(const f32x4*)&be[c0 + q * 4];
#pragma unroll
        for (int e = 0; e < 4; e++)
            ov[q * 4 + e] = (v[q * 4 + e] - mu) * rs * gv[e] + bv[e];
    }
    if (OUTF32) {
#pragma unroll
        for (int q = 0; q < 4; q++) {
            f32x4 o;
#pragma unroll
            for (int e = 0; e < 4; e++) o[e] = ov[q * 4 + e];
            *((f32x4*)((float*)out + off) + q) = o;
        }
    } else {
#pragma unroll
        for (int q = 0; q < 2; q++) {
            u16x8 o;
#pragma unroll
            for (int e = 0; e < 8; e++) o[e] = f2bf(ov[q * 8 + e]);
            *((u16x8*)((u16*)out + off) + q) = o;
        }
    }
}

// ---------------------------------------------------------------------------
// Flash cross-attention. Grid: (8 i-tiles, 16 heads, 4 b). T5 setprio.
// K/V LDS tiles are 64x64 (128B row stride) -> same swizzle as gemm_body:
// slot(c,r) = c ^ (r&7), via permuted global source + XOR'd ds_read.
// ---------------------------------------------------------------------------
__global__ __launch_bounds__(256, 3)
void flash_ca(const u16* __restrict__ P, const u16* __restrict__ Kc,
              const u16* __restrict__ VT, u16* __restrict__ O)
{
    __shared__ alignas(16) u16 Ks[2][64 * 64];
    __shared__ alignas(16) u16 Vs[2][64 * 64];   // [d][j]
    __shared__ alignas(16) u16 Ps[128 * 72];     // per-wave 32-row strips
    const int b = blockIdx.z, h = blockIdx.y, it = blockIdx.x;
    const long base = (long)b * N_ * D_;
    const int t = threadIdx.x, lane = t & 63, w = t >> 6;
    const int fr = lane & 15, fq = lane >> 4;

    bf16x8 qf[2][2];
#pragma unroll
    for (int mt = 0; mt < 2; mt++)
#pragma unroll
        for (int hf = 0; hf < 2; hf++)
            qf[mt][hf] = ld8(&P[base + (long)(it * 128 + w * 32 + mt * 16 + fr) * D_
                                + h * 64 + hf * 32 + fq * 8]);

    // staging: thread t -> row (t>>3), dest slot (t&7); global chunk = slot ^ (row&7)
    const int svr = t >> 3, svc = ((t & 7) ^ (svr & 7)) * 8;
    auto stageK = [&](int buf, int jt) {
#pragma unroll
        for (int p = 0; p < 2; p++)
            gll16(Kc + base + (long)(jt * 64 + p * 32 + svr) * D_ + h * 64 + svc,
                  &Ks[buf][p * 2048 + w * 512]);
    };
    auto stageV = [&](int buf, int jt) {
#pragma unroll
        for (int p = 0; p < 2; p++)
            gll16(VT + base + (long)(h * 64 + p * 32 + svr) * D_ + jt * 64 + svc,
                  &Vs[buf][p * 2048 + w * 512]);
    };

    f32x4 o[2][4] = {};
    float l_lane[2][4] = {};

    stageK(0, 0); stageV(0, 0);
    int cur = 0;
    for (int jt = 0; jt < 16; jt++) {
        __syncthreads();
        if (jt + 1 < 16) { stageK(cur ^ 1, jt + 1); stageV(cur ^ 1, jt + 1); }
        const u16* ks = Ks[cur];
        const u16* vs = Vs[cur];

        f32x4 st[2][4] = {};
        __builtin_amdgcn_s_setprio(1);
#pragma unroll
        for (int nt = 0; nt < 4; nt++) {
            const int row = nt * 16 + fr;
            bf16x8 b0 = ld8(&ks[row * 64 + ((fq ^ (row & 7)) << 3)]);
            bf16x8 b1 = ld8(&ks[row * 64 + (((fq + 4) ^ (row & 7)) << 3)]);
#pragma unroll
            for (int mt = 0; mt < 2; mt++) {
                st[mt][nt] = __builtin_amdgcn_mfma_f32_16x16x32_bf16(qf[mt][0], b0, st[mt][nt], 0, 0, 0);
                st[mt][nt] = __builtin_amdgcn_mfma_f32_16x16x32_bf16(qf[mt][1], b1, st[mt][nt], 0, 0, 0);
            }
        }
        __builtin_amdgcn_s_setprio(0);
#pragma unroll
        for (int mt = 0; mt < 2; mt++)
#pragma unroll
            for (int nt = 0; nt < 4; nt++)
#pragma unroll
                for (int r = 0; r < 4; r++) {
                    float e = __expf(st[mt][nt][r]);
                    l_lane[mt][r] += e;
                    Ps[(w * 32 + mt * 16 + fq * 4 + r) * 72 + nt * 16 + fr] = f2bf(e);
                }
        __asm__ volatile("s_waitcnt lgkmcnt(0)" ::: "memory");
        bf16x8 vf[4][2];
#pragma unroll
        for (int dt = 0; dt < 4; dt++) {
            const int row = dt * 16 + fr;
            vf[dt][0] = ld8(&vs[row * 64 + ((fq ^ (row & 7)) << 3)]);
            vf[dt][1] = ld8(&vs[row * 64 + (((fq + 4) ^ (row & 7)) << 3)]);
        }
        __builtin_amdgcn_s_setprio(1);
#pragma unroll
        for (int mt = 0; mt < 2; mt++) {
            bf16x8 p0 = ld8(&Ps[(w * 32 + mt * 16 + fr) * 72 + fq * 8]);
            bf16x8 p1 = ld8(&Ps[(w * 32 + mt * 16 + fr) * 72 + 32 + fq * 8]);
#pragma unroll
            for (int dt = 0; dt < 4; dt++) {
                o[mt][dt] = __builtin_amdgcn_mfma_f32_16x16x32_bf16(p0, vf[dt][0], o[mt][dt], 0, 0, 0);
                o[mt][dt] = __builtin_amdgcn_mfma_f32_16x16x32_bf16(p1, vf[dt][1], o[mt][dt], 0, 0, 0);
            }
        }
        __builtin_amdgcn_s_setprio(0);
        cur ^= 1;
    }
#pragma unroll
    for (int mt = 0; mt < 2; mt++)
#pragma unroll
        for (int r = 0; r < 4; r++) {
            float lt = l_lane[mt][r];
#pragma unroll
            for (int off = 1; off < 16; off <<= 1) lt += __shfl_xor(lt, off, 64);
            l_lane[mt][r] = 1.0f / lt;
        }
#pragma unroll
    for (int mt = 0; mt < 2; mt++)
#pragma unroll
        for (int dt = 0; dt < 4; dt++)
#pragma unroll
            for (int r = 0; r < 4; r++)
                O[base + (long)(it * 128 + w * 32 + mt * 16 + fq * 4 + r) * D_
                  + h * 64 + dt * 16 + fr] = f2bf(o[mt][dt][r] * l_lane[mt][r]);
}

// ---------------------------------------------------------------------------
extern "C" void kernel_launch(void* const* d_in, const int* in_sizes, int n_in,
                              void* d_out, int out_size, void* d_ws, size_t ws_size,
                              hipStream_t stream)
{
    const float* x     = (const float*)d_in[0];
    const float* enc   = (const float*)d_in[1];
    const float* sa_wq = (const float*)d_in[2];
    const float* sa_wk = (const float*)d_in[3];
    const float* sa_wv = (const float*)d_in[4];
    const float* sa_g  = (const float*)d_in[5];
    const float* sa_b  = (const float*)d_in[6];
    const float* ca_wq = (const float*)d_in[7];
    const float* ca_wk = (const float*)d_in[8];
    const float* ca_wv = (const float*)d_in[9];
    const float* ca_g  = (const float*)d_in[10];
    const float* ca_b  = (const float*)d_in[11];
    const float* w1    = (const float*)d_in[12];
    const float* b1    = (const float*)d_in[13];
    const float* w2    = (const float*)d_in[14];
    const float* b2    = (const float*)d_in[15];
    const float* ff_g  = (const float*)d_in[16];
    const float* ff_b  = (const float*)d_in[17];

    // 76 MB workspace, lifetime-overlaid (MB offsets):
    //  0- 8 xB -> attnB(attn->P) -> w2T
    //  8-16 encB -> w1T
    // 16-22 Wsa ; 22-28 Wca ; 16-32 h2F (after CA)
    // 28-36 qB_sa -> E(saln) -> flash O
    // 36-44 kB_sa -> qB(ca) -> calnB
    // 44-52 vTB -> kB(ca) ; 44-76 h1B (FF)
    // 52-60 vcTB
    // 60-76 scF (fp32) ; 60-68 kcT (CA)
    char* ws = (char*)d_ws;
    const size_t MB = 1ull << 20;
    u16*  xB    = (u16*)(ws + 0 * MB);
    u16*  attnB = (u16*)(ws + 0 * MB);
    u16*  w2T   = (u16*)(ws + 0 * MB);
    u16*  encB  = (u16*)(ws + 8 * MB);
    u16*  w1T   = (u16*)(ws + 8 * MB);
    u16*  Wsa   = (u16*)(ws + 16 * MB);   // q@+0, k@+1M, v@+2M elems
    u16*  Wca   = (u16*)(ws + 22 * MB);
    float* h2F  = (float*)(ws + 16 * MB);
    u16*  qBsa  = (u16*)(ws + 28 * MB);
    u16*  E     = (u16*)(ws + 28 * MB);   // saln, then flash O
    u16*  kBsa  = (u16*)(ws + 36 * MB);
    u16*  qBca  = (u16*)(ws + 36 * MB);
    u16*  calnB = (u16*)(ws + 36 * MB);
    u16*  vTB   = (u16*)(ws + 44 * MB);
    u16*  kBca  = (u16*)(ws + 44 * MB);
    u16*  h1B   = (u16*)(ws + 44 * MB);
    u16*  vcTB  = (u16*)(ws + 52 * MB);
    float* scF  = (float*)(ws + 60 * MB);
    u16*  kcT   = (u16*)(ws + 60 * MB);

    const dim3 blk(256, 1, 1);
    const long M1 = (long)N_ * D_;        // 1M elems, per-batch stride
    const long W1M = (long)1024 * 1024;   // weight matrix elems

    // 0) fused prep: x|enc converts + six weight transposes (one dispatch)
    prep_all<<<dim3(10240, 1, 1), blk, 0, stream>>>(
        x, enc, xB, encB, sa_wq, sa_wk, sa_wv, ca_wq, ca_wk, ca_wv, Wsa, Wca);

    // 2) q|k|vT|vcT merged: 1024 blocks of 128x128, 4 blocks/CU.
    gemm_qkv4<<<dim3(1024, 1, 1), blk, 0, stream>>>(
        xB, Wsa, Wsa + W1M, qBsa, kBsa,
        Wsa + 2 * W1M, Wca + 2 * W1M, encB, vTB, vcTB);
    // 4) scores = q k^T / 32 (fp32). grid 8x16x4 = 512, 128x64, BK=64.
    gemm_a<128,64,64,0,1,0,0><<<dim3(8, 16, 4), blk, 0, stream>>>(
        qBsa, nullptr, kBsa, nullptr, scF, nullptr, nullptr,
        0.03125f, 1024, 1024, 1024, 1024, M1, M1, M1);
    softmax_1024<<<dim3(1024, 1, 1), blk, 0, stream>>>(scF, attnB);
    // 5) sa_pre = attn @ v (fp32), BK=64
    gemm_a<128,64,64,0,1,0,0><<<dim3(8, 16, 4), blk, 0, stream>>>(
        attnB, nullptr, vTB, nullptr, scF, nullptr, nullptr,
        1.f, 1024, 1024, 1024, 1024, M1, M1, M1);
    ln_res<1,1,0><<<dim3(1024, 1, 1), blk, 0, stream>>>(scF, x, sa_g, sa_b, E);

    // 6) qc|kc fused (y-half): qc = saln @ Wq ; kc = encB @ Wk. BK=64.
    gemm_a<128,128,64,1,0,0,0><<<dim3(32, 16, 1), blk, 0, stream>>>(
        E, encB, Wca, Wca + W1M, qBca, kBca, nullptr,
        1.f, 1024, 1024, 1024, 1024, 0, 0, 0);
    // 7) kcT per batch (scF dead)
    transpose_cast<0><<<dim3(32, 32, 4), blk, 0, stream>>>(kBca, kcT, 1024, 1024, M1, M1);
    // 8) P = (qc @ kc) / 64, BK=64
    gemm_a<128,64,64,0,0,0,0><<<dim3(8, 16, 4), blk, 0, stream>>>(
        qBca, nullptr, kcT, nullptr, attnB, nullptr, nullptr,
        0.015625f, 1024, 1024, 1024, 1024, M1, M1, M1);
    // 9) flash cross-attn -> O (over saln region)
    flash_ca<<<dim3(8, 16, 4), blk, 0, stream>>>(attnB, kBca, vcTB, E);
    ln_res<0,1,0><<<dim3(1024, 1, 1), blk, 0, stream>>>(E, enc, ca_g, ca_b, calnB);

    // 10) FeedForward (w1T|w2T fused in one dispatch)
    transpose_ff<<<dim3(128, 32, 2), blk, 0, stream>>>(w1, w2, w1T, w2T);
    gemm_a<128,128,32,0,0,1,1><<<dim3(32, 32, 1), blk, 0, stream>>>(
        calnB, nullptr, w1T, nullptr, h1B, nullptr, b1,
        1.f, 1024, 1024, 1024, 4096, 0, 0, 0);
    gemm_a<128,64,64,0,1,1,0><<<dim3(32, 16, 1), blk, 0, stream>>>(
        h1B, nullptr, w2T, nullptr, h2F, nullptr, b2,
        1.f, 4096, 4096, 4096, 1024, 0, 0, 0);
    ln_res<1,0,1><<<dim3(1024, 1, 1), blk, 0, stream>>>(h2F, calnB, ff_g, ff_b, (float*)d_out);
}